// Round 1
// 442.874 us; speedup vs baseline: 1.0856x; 1.0856x over previous
//
#include <hip/hip_runtime.h>

typedef unsigned short ushort_t;
typedef unsigned int uint32;
typedef __bf16 bf16x8 __attribute__((ext_vector_type(8)));
typedef float f32x4 __attribute__((ext_vector_type(4)));
typedef uint32 u32x4 __attribute__((ext_vector_type(4)));
typedef uint32 u32x2 __attribute__((ext_vector_type(2)));

__device__ __forceinline__ float bf2f(ushort_t u) {
    uint32 x = ((uint32)u) << 16;
    return __builtin_bit_cast(float, x);
}
__device__ __forceinline__ ushort_t f2bf(float f) {
    uint32 x = __builtin_bit_cast(uint32, f);
    x += 0x7fffu + ((x >> 16) & 1u);   // RNE
    return (ushort_t)(x >> 16);
}
// load 4 consecutive bf16 -> 4 floats (8B vector load)
__device__ __forceinline__ void ld4bf(const ushort_t* p, float* f) {
    const u32x2 w = *(const u32x2*)p;
    f[0] = bf2f((ushort_t)(w[0] & 0xffffu)); f[1] = bf2f((ushort_t)(w[0] >> 16));
    f[2] = bf2f((ushort_t)(w[1] & 0xffffu)); f[3] = bf2f((ushort_t)(w[1] >> 16));
}
// pack 4 floats -> 4 bf16 (8B)
__device__ __forceinline__ u32x2 pk4bf(const float* v) {
    u32x2 pk;
    pk[0] = (uint32)f2bf(v[0]) | ((uint32)f2bf(v[1]) << 16);
    pk[1] = (uint32)f2bf(v[2]) | ((uint32)f2bf(v[3]) << 16);
    return pk;
}

// fused dtype-sniff + small-vector canon: 1 launch instead of 2
struct VecArgs { const void* s[13]; ushort_t* d[13]; int n[13]; };
__global__ void sniff_vec_kernel(const uint32* __restrict__ src, int* __restrict__ flag,
                                 VecArgs a) {
    __shared__ int cnt;
    if (threadIdx.x == 0) cnt = 0;
    __syncthreads();
    if (threadIdx.x < 64) {
        int weird = 0;
        for (int c = 0; c < 4; c++) {
            uint32 w = src[threadIdx.x * 4 + c];
            uint32 e = (w >> 7) & 0xFFu;
            weird += (e < 64u) || (e >= 192u);
        }
        if (weird) atomicAdd(&cnt, weird);
    }
    __syncthreads();
    const bool isf32 = (cnt > 32);
    if (threadIdx.x == 0) *flag = isf32 ? 1 : 0;
    const int t = threadIdx.x;
    for (int seg = 0; seg < 13; seg++) {
        const int n = a.n[seg];
        if (isf32) {
            const float* s = (const float*)a.s[seg];
            for (int i = t; i < n; i += 256) a.d[seg][i] = f2bf(s[i]);
        } else {
            const ushort_t* s = (const ushort_t*)a.s[seg];
            for (int i = t; i < n; i += 256) a.d[seg][i] = s[i];
        }
    }
}

// vectorized big canon: 8 elems/thread/iter (n % 8 == 0 for all uses)
__global__ void canon_kernel(const void* __restrict__ src, ushort_t* __restrict__ dst,
                             long n, const int* __restrict__ flag) {
    const bool isf32 = (*flag != 0);
    long i = ((long)blockIdx.x * blockDim.x + threadIdx.x) * 8;
    const long stride = (long)gridDim.x * blockDim.x * 8;
    if (isf32) {
        const float* s = (const float*)src;
        for (; i < n; i += stride) {
            const f32x4 a = *(const f32x4*)(s + i);
            const f32x4 b = *(const f32x4*)(s + i + 4);
            u32x4 o;
            o[0] = (uint32)f2bf(a[0]) | ((uint32)f2bf(a[1]) << 16);
            o[1] = (uint32)f2bf(a[2]) | ((uint32)f2bf(a[3]) << 16);
            o[2] = (uint32)f2bf(b[0]) | ((uint32)f2bf(b[1]) << 16);
            o[3] = (uint32)f2bf(b[2]) | ((uint32)f2bf(b[3]) << 16);
            *(u32x4*)(dst + i) = o;
        }
    } else {
        const ushort_t* s = (const ushort_t*)src;
        for (; i < n; i += stride)
            *(u32x4*)(dst + i) = *(const u32x4*)(s + i);
    }
}

// all 5 weight transpose-canons in one launch (blockIdx.z selects weight)
struct WtArgs { const void* s[5]; ushort_t* d[5]; int R[5]; int C[5]; };
__global__ void wt_canon_all(WtArgs a, const int* __restrict__ flag) {
    const int wsel = blockIdx.z;
    const int R = a.R[wsel], C = a.C[wsel];
    const int tr = blockIdx.y, tc = blockIdx.x;
    if (tc * 32 >= C || tr * 32 >= R) return;   // block-uniform skip
    __shared__ float s[32][33];
    const bool isf32 = (*flag != 0);
    const int t = threadIdx.x;
    const int r = t >> 3, c4 = (t & 7) * 4;
    const long sbase = (long)(tr * 32 + r) * C + tc * 32 + c4;
    if (isf32) {
        const float* S = (const float*)a.s[wsel];
        const f32x4 v = *(const f32x4*)(S + sbase);
        for (int u = 0; u < 4; u++) s[r][c4 + u] = v[u];
    } else {
        const ushort_t* S = (const ushort_t*)a.s[wsel];
        for (int u = 0; u < 4; u++) s[r][c4 + u] = bf2f(S[sbase + u]);
    }
    __syncthreads();
    float tv[4];
    for (int u = 0; u < 4; u++) tv[u] = s[c4 + u][r];
    *(u32x2*)(a.d[wsel] + (long)(tc * 32 + r) * R + tr * 32 + c4) = pk4bf(tv);
}

// reduce 4 fp32 split-K partials + transposed bf16 store:
// out[b][n][m] = bf16( sum_{kc<4} P[(b*4+kc)*65536 + m*256 + n] )
__global__ void reduce_t_kernel(const float* __restrict__ P, ushort_t* __restrict__ out) {
    __shared__ float s[32][33];
    const int b = blockIdx.z, tm = blockIdx.y, tn = blockIdx.x;
    const int t = threadIdx.x;
    const int r = t >> 3, c4 = (t & 7) * 4;
    const float* base = P + (long)b * 4 * 65536 + (long)(tm * 32 + r) * 256 + tn * 32 + c4;
    f32x4 acc = {0.f, 0.f, 0.f, 0.f};
    for (int kc = 0; kc < 4; kc++) acc += *(const f32x4*)(base + (long)kc * 65536);
    for (int u = 0; u < 4; u++) s[r][c4 + u] = acc[u];
    __syncthreads();
    float tv[4];
    for (int u = 0; u < 4; u++) tv[u] = s[c4 + u][r];
    *(u32x2*)(out + (long)b * 65536 + (long)(tn * 32 + r) * 256 + tm * 32 + c4) = pk4bf(tv);
}

#define BM 128
#define BN 128
#define BK 32
#define LDSS 40

enum { EPI_BIAS = 0, EPI_BIASR = 1, EPI_SCALE = 2, EPI_BN = 3, EPI_PART = 4 };

// NT GEMM: C[m][n] = sum_k A[m][k] * B[n][k], both operands k-contiguous.
// Grid covers exactly (N/BN, M/BM, Z). Per-z offsets: A+=z*sA, B+=z*sB, cbase=coff+z*sC.
// EPI_PART: fp32 store (split-K partial). DUALT: also store bf16 C^T at CT (ldT).
// SWAP: compute mfma(b,a) -> transposed fragment: thread holds 4 CONSECUTIVE cols
// at fixed row -> vector epilogue (f32x4 / u32x2 stores, u32x2 res/param loads).
template <int EPI, bool DYNOUT, bool DUALT, bool SWAP>
__global__ __launch_bounds__(256) void gemm_nt(
    const ushort_t* __restrict__ A, const ushort_t* __restrict__ B,
    void* __restrict__ Cv, long coff,
    int K, int lda, int ldb, int ldc,
    long sA, long sB, long sC,
    ushort_t* __restrict__ CT, int ldT,
    const ushort_t* __restrict__ bias,
    const ushort_t* __restrict__ gamma, const ushort_t* __restrict__ beta,
    const ushort_t* __restrict__ mean, const ushort_t* __restrict__ var,
    const ushort_t* __restrict__ res,
    float alpha, const int* __restrict__ flag)
{
    __shared__ __align__(16) ushort_t As[BM * LDSS];
    __shared__ __align__(16) ushort_t Bs[BN * LDSS];

    const bool isf32 = DYNOUT ? (*flag != 0) : false;

    const int z = blockIdx.z;
    A += (long)z * sA;
    B += (long)z * sB;
    const long cbase = coff + (long)z * sC;

    const int tid  = threadIdx.x;
    const int lane = tid & 63;
    const int w    = tid >> 6;
    const int wr   = w >> 1, wc = w & 1;
    const int lr   = lane & 15, q = lane >> 4;

    const int m0 = blockIdx.y * BM;
    const int n0 = blockIdx.x * BN;

    f32x4 acc[4][4];
#pragma unroll
    for (int i = 0; i < 4; i++)
#pragma unroll
        for (int j = 0; j < 4; j++) acc[i][j] = (f32x4){0.f, 0.f, 0.f, 0.f};

    for (int k0 = 0; k0 < K; k0 += BK) {
#pragma unroll
        for (int c = 0; c < 2; c++) {
            const int ch = tid + c * 256;
            const int r = ch >> 2, qq = ch & 3;
            *(u32x4*)(&As[r * LDSS + qq * 8]) =
                *(const u32x4*)(A + (long)(m0 + r) * lda + k0 + qq * 8);
        }
#pragma unroll
        for (int c = 0; c < 2; c++) {
            const int ch = tid + c * 256;
            const int r = ch >> 2, qq = ch & 3;
            *(u32x4*)(&Bs[r * LDSS + qq * 8]) =
                *(const u32x4*)(B + (long)(n0 + r) * ldb + k0 + qq * 8);
        }
        __syncthreads();

        bf16x8 af[4], bfr[4];
#pragma unroll
        for (int i = 0; i < 4; i++)
            af[i] = __builtin_bit_cast(bf16x8,
                *(const u32x4*)(&As[(wr * 64 + i * 16 + lr) * LDSS + q * 8]));
#pragma unroll
        for (int j = 0; j < 4; j++)
            bfr[j] = __builtin_bit_cast(bf16x8,
                *(const u32x4*)(&Bs[(wc * 64 + j * 16 + lr) * LDSS + q * 8]));
#pragma unroll
        for (int i = 0; i < 4; i++)
#pragma unroll
            for (int j = 0; j < 4; j++) {
                if constexpr (SWAP)
                    acc[i][j] = __builtin_amdgcn_mfma_f32_16x16x32_bf16(bfr[j], af[i], acc[i][j], 0, 0, 0);
                else
                    acc[i][j] = __builtin_amdgcn_mfma_f32_16x16x32_bf16(af[i], bfr[j], acc[i][j], 0, 0, 0);
            }
        __syncthreads();
    }

    if constexpr (SWAP) {
        // D layout (swapped): col=lane&15 -> m index, row=(lane>>4)*4+reg -> n index.
        // Thread holds C[m0+..+lr][n0+..+q*4 .. +3]: 4 consecutive cols -> vector stores.
#pragma unroll
        for (int j = 0; j < 4; j++) {
            const int coln = n0 + wc * 64 + j * 16 + q * 4;
            float sc4[4], sh4[4];
            if constexpr (EPI == EPI_BIAS) {
                float bb[4]; ld4bf(bias + coln, bb);
#pragma unroll
                for (int r = 0; r < 4; r++) { sc4[r] = 1.f; sh4[r] = bb[r]; }
            } else if constexpr (EPI == EPI_SCALE) {
#pragma unroll
                for (int r = 0; r < 4; r++) { sc4[r] = alpha; sh4[r] = 0.f; }
            } else if constexpr (EPI == EPI_BN) {
                float bb[4], g[4], bt[4], mn[4], vr[4];
                ld4bf(bias + coln, bb); ld4bf(gamma + coln, g); ld4bf(beta + coln, bt);
                ld4bf(mean + coln, mn); ld4bf(var + coln, vr);
#pragma unroll
                for (int r = 0; r < 4; r++) {
                    const float s = g[r] * rsqrtf(vr[r] + 1e-3f);
                    sc4[r] = s;
                    sh4[r] = s * bb[r] + bt[r] - s * mn[r];
                }
            }
#pragma unroll
            for (int i = 0; i < 4; i++) {
                const int row = m0 + wr * 64 + i * 16 + lr;
                const long off = cbase + (long)row * ldc + coln;
                float v[4];
#pragma unroll
                for (int r = 0; r < 4; r++) v[r] = acc[i][j][r];
                if constexpr (EPI == EPI_BIASR) {
                    const float bs = bf2f(bias[row]);
#pragma unroll
                    for (int r = 0; r < 4; r++) v[r] += bs;
                } else if constexpr (EPI == EPI_BN) {
                    float rs[4]; ld4bf(res + (long)row * ldc + coln, rs);
#pragma unroll
                    for (int r = 0; r < 4; r++) v[r] = sc4[r] * v[r] + sh4[r] + rs[r];
                } else if constexpr (EPI != EPI_PART) {
#pragma unroll
                    for (int r = 0; r < 4; r++) v[r] = sc4[r] * v[r] + sh4[r];
                }
                if constexpr (EPI == EPI_PART) {
                    *(f32x4*)((float*)Cv + off) = (f32x4){v[0], v[1], v[2], v[3]};
                } else if constexpr (DYNOUT) {
                    if (isf32) *(f32x4*)((float*)Cv + off) = (f32x4){v[0], v[1], v[2], v[3]};
                    else       *(u32x2*)((ushort_t*)Cv + off) = pk4bf(v);
                } else {
                    *(u32x2*)((ushort_t*)Cv + off) = pk4bf(v);
                }
            }
        }
    } else {
        // D layout: col=lane&15 -> n, row=(lane>>4)*4+reg -> m  [verified]
#pragma unroll
        for (int j = 0; j < 4; j++) {
            const int col = n0 + wc * 64 + j * 16 + lr;
            float bs = 0.f, sc = 1.f, sh = 0.f;
            if constexpr (EPI == EPI_BIAS || EPI == EPI_BN) bs = bf2f(bias[col]);
            if constexpr (EPI == EPI_BN) {
                const float g  = bf2f(gamma[col]);
                const float bt = bf2f(beta[col]);
                const float mn = bf2f(mean[col]);
                const float vr = bf2f(var[col]);
                sc = g * rsqrtf(vr + 1e-3f);
                sh = bt - sc * mn;
            }
#pragma unroll
            for (int i = 0; i < 4; i++) {
                const int rowbase = m0 + wr * 64 + i * 16 + q * 4;
                ushort_t tmp[4];
#pragma unroll
                for (int r = 0; r < 4; r++) {
                    const int row = rowbase + r;
                    float v = acc[i][j][r];
                    if constexpr (EPI == EPI_BIAS) v += bs;
                    else if constexpr (EPI == EPI_BIASR) v += bf2f(bias[row]);
                    else if constexpr (EPI == EPI_SCALE) v *= alpha;
                    else if constexpr (EPI == EPI_BN)
                        v = sc * (v + bs) + sh + bf2f(res[(long)row * ldc + col]);
                    const long off = cbase + (long)row * ldc + col;
                    if constexpr (EPI == EPI_PART) {
                        ((float*)Cv)[off] = v;
                    } else if constexpr (DYNOUT) {
                        if (isf32) ((float*)Cv)[off] = v;
                        else       ((ushort_t*)Cv)[off] = f2bf(v);
                    } else {
                        const ushort_t us = f2bf(v);
                        ((ushort_t*)Cv)[off] = us;
                        if constexpr (DUALT) tmp[r] = us;
                    }
                }
                if constexpr (DUALT) {
                    u32x2 pk;
                    pk[0] = (uint32)tmp[0] | ((uint32)tmp[1] << 16);
                    pk[1] = (uint32)tmp[2] | ((uint32)tmp[3] << 16);
                    *(u32x2*)(CT + (long)col * ldT + rowbase) = pk;
                }
            }
        }
    }
}

extern "C" void kernel_launch(void* const* d_in, const int* in_sizes, int n_in,
                              void* d_out, int out_size, void* d_ws, size_t ws_size,
                              hipStream_t stream)
{
    int* flag = (int*)d_ws;
    ushort_t* base = (ushort_t*)((char*)d_ws + 16);
    long o = 0;
    ushort_t* detect_c = base + o; o += 16777216;   // [32768][512]
    ushort_t* aim_c    = base + o; o += 4194304;    // [8192][512]
    ushort_t* WgT  = base + o; o += 131072;         // [256][512]
    ushort_t* WtT  = base + o; o += 131072;
    ushort_t* WpT  = base + o; o += 131072;
    ushort_t* WwT  = base + o; o += 131072;         // [512][256]
    ushort_t* WqT  = base + o; o += 131072;
    ushort_t* bg_c   = base + o; o += 256;
    ushort_t* bt_c   = base + o; o += 256;
    ushort_t* bp_c   = base + o; o += 256;
    ushort_t* bw_c   = base + o; o += 512;
    ushort_t* gw_c   = base + o; o += 512;
    ushort_t* betw_c = base + o; o += 512;
    ushort_t* mw_c   = base + o; o += 512;
    ushort_t* vw_c   = base + o; o += 512;
    ushort_t* bq_c   = base + o; o += 512;
    ushort_t* gq_c   = base + o; o += 512;
    ushort_t* betq_c = base + o; o += 512;
    ushort_t* mq_c   = base + o; o += 512;
    ushort_t* vq_c   = base + o; o += 512;
    ushort_t* phi    = base + o; o += 8388608;      // [32768][256]
    ushort_t* phiT   = base + o; o += 8388608;      // [256][32768]
    ushort_t* d_xT   = base + o; o += 8388608;      // [256][32768]
    ushort_t* theta  = base + o; o += 2097152;      // [8192][256]
    ushort_t* thetaT = base + o; o += 2097152;      // [256][8192]
    ushort_t* a_xT   = base + o; o += 2097152;      // [256][8192]
    ushort_t* G1T    = base + o; o += 524288;       // [8][256][256]
    ushort_t* G2T    = base + o; o += 524288;
    // union region: P1,P2 (fp32, lifetime ends at reduces) then na,nd
    ushort_t* U      = base + o; o += 10485760;     // 21 MB
    float* P1 = (float*)U;                          // 32 x 65536 fp32
    float* P2 = P1 + 2097152;
    ushort_t* na = U;                               // [8192][256]
    ushort_t* nd = na + 2097152;                    // [32768][256]
    // total ~123 MiB

    // canon: sniff + vectors fused; weights (one transposed launch); activations
    VecArgs va;
    const int vidx[13] = {3, 5, 7, 9, 10, 11, 12, 13, 15, 16, 17, 18, 19};
    ushort_t* vdst[13] = {bg_c, bt_c, bp_c, bw_c, gw_c, betw_c, mw_c, vw_c,
                          bq_c, gq_c, betq_c, mq_c, vq_c};
    const int vn[13] = {256, 256, 256, 512, 512, 512, 512, 512, 512, 512, 512, 512, 512};
    for (int i = 0; i < 13; i++) { va.s[i] = d_in[vidx[i]]; va.d[i] = vdst[i]; va.n[i] = vn[i]; }
    sniff_vec_kernel<<<1, 256, 0, stream>>>((const uint32*)d_in[0], flag, va);

    WtArgs wa;
    wa.s[0] = d_in[2];  wa.d[0] = WgT; wa.R[0] = 512; wa.C[0] = 256;
    wa.s[1] = d_in[4];  wa.d[1] = WtT; wa.R[1] = 512; wa.C[1] = 256;
    wa.s[2] = d_in[6];  wa.d[2] = WpT; wa.R[2] = 512; wa.C[2] = 256;
    wa.s[3] = d_in[8];  wa.d[3] = WwT; wa.R[3] = 256; wa.C[3] = 512;
    wa.s[4] = d_in[14]; wa.d[4] = WqT; wa.R[4] = 256; wa.C[4] = 512;
    wt_canon_all<<<dim3(16, 16, 5), 256, 0, stream>>>(wa, flag);

    canon_kernel<<<2048, 256, 0, stream>>>(d_in[0], detect_c, 16777216, flag);
    canon_kernel<<<1024, 256, 0, stream>>>(d_in[1], aim_c, 4194304, flag);

    const dim3 blk(256);
    const ushort_t* np = nullptr;
    ushort_t* npm = nullptr;

    // conv phi: [32768][256] + dual-T [256][32768]  (unswapped: CT store is vectorized)
    gemm_nt<EPI_BIAS, false, true, false><<<dim3(2, 256, 1), blk, 0, stream>>>(
        detect_c, WpT, phi, 0, 512, 512, 512, 256, 0, 0, 0,
        phiT, 32768, bp_c, np, np, np, np, np, 1.f, flag);
    // conv theta: [8192][256] + dual-T [256][8192]
    gemm_nt<EPI_BIAS, false, true, false><<<dim3(2, 64, 1), blk, 0, stream>>>(
        aim_c, WtT, theta, 0, 512, 512, 512, 256, 0, 0, 0,
        thetaT, 8192, bt_c, np, np, np, np, np, 1.f, flag);
    // conv d_xT (transposed orientation): C[ci][spatial], row-bias  (SWAP: u32x2 stores)
    gemm_nt<EPI_BIASR, false, false, true><<<dim3(256, 2, 1), blk, 0, stream>>>(
        WgT, detect_c, d_xT, 0, 512, 512, 512, 32768, 0, 0, 0,
        npm, 0, bg_c, np, np, np, np, np, 1.f, flag);
    // conv a_xT
    gemm_nt<EPI_BIASR, false, false, true><<<dim3(64, 2, 1), blk, 0, stream>>>(
        WgT, aim_c, a_xT, 0, 512, 512, 512, 8192, 0, 0, 0,
        npm, 0, bg_c, np, np, np, np, np, 1.f, flag);

    // G1 partials: z=b*4+kc, K-chunk 1024 (SWAP: f32x4 stores)
    gemm_nt<EPI_PART, false, false, true><<<dim3(2, 2, 32), blk, 0, stream>>>(
        phiT, d_xT, P1, 0, 1024, 32768, 32768, 256, 1024, 1024, 65536,
        npm, 0, np, np, np, np, np, np, 1.f, flag);
    // G2 partials: K-chunk 256
    gemm_nt<EPI_PART, false, false, true><<<dim3(2, 2, 32), blk, 0, stream>>>(
        thetaT, a_xT, P2, 0, 256, 8192, 8192, 256, 256, 256, 65536,
        npm, 0, np, np, np, np, np, np, 1.f, flag);

    reduce_t_kernel<<<dim3(8, 8, 8), blk, 0, stream>>>(P1, G1T);
    reduce_t_kernel<<<dim3(8, 8, 8), blk, 0, stream>>>(P2, G2T);

    // na = theta @ G1 / 4096  (B = G1T, NT; SWAP: u32x2 stores)
    gemm_nt<EPI_SCALE, false, false, true><<<dim3(2, 8, 8), blk, 0, stream>>>(
        theta, G1T, na, 0, 256, 256, 256, 256, 262144, 65536, 262144,
        npm, 0, np, np, np, np, np, np, 1.f / 4096.f, flag);
    // nd = phi @ G2 / 1024
    gemm_nt<EPI_SCALE, false, false, true><<<dim3(2, 32, 8), blk, 0, stream>>>(
        phi, G2T, nd, 0, 256, 256, 256, 256, 1048576, 65536, 1048576,
        npm, 0, np, np, np, np, np, np, 1.f / 1024.f, flag);

    // out0 = BN(na @ Ww + bw) + aim  (SWAP: f32x4 out, u32x2 res reads)
    gemm_nt<EPI_BN, true, false, true><<<dim3(4, 64, 1), blk, 0, stream>>>(
        na, WwT, d_out, 0, 256, 256, 256, 512, 0, 0, 0,
        npm, 0, bw_c, gw_c, betw_c, mw_c, vw_c, aim_c, 1.f, flag);
    // out1 = BN(nd @ Wq + bq) + detect
    gemm_nt<EPI_BN, true, false, true><<<dim3(4, 256, 1), blk, 0, stream>>>(
        nd, WqT, d_out, 8192L * 512, 256, 256, 256, 512, 0, 0, 0,
        npm, 0, bq_c, gq_c, betq_c, mq_c, vq_c, detect_c, 1.f, flag);
}

// Round 2
// 425.064 us; speedup vs baseline: 1.1311x; 1.0419x over previous
//
#include <hip/hip_runtime.h>

typedef unsigned short ushort_t;
typedef unsigned int uint32;
typedef __bf16 bf16x8 __attribute__((ext_vector_type(8)));
typedef float f32x4 __attribute__((ext_vector_type(4)));
typedef uint32 u32x4 __attribute__((ext_vector_type(4)));
typedef uint32 u32x2 __attribute__((ext_vector_type(2)));

__device__ __forceinline__ float bf2f(ushort_t u) {
    uint32 x = ((uint32)u) << 16;
    return __builtin_bit_cast(float, x);
}
__device__ __forceinline__ ushort_t f2bf(float f) {
    uint32 x = __builtin_bit_cast(uint32, f);
    x += 0x7fffu + ((x >> 16) & 1u);   // RNE
    return (ushort_t)(x >> 16);
}
// load 4 consecutive bf16 -> 4 floats (8B vector load)
__device__ __forceinline__ void ld4bf(const ushort_t* p, float* f) {
    const u32x2 w = *(const u32x2*)p;
    f[0] = bf2f((ushort_t)(w[0] & 0xffffu)); f[1] = bf2f((ushort_t)(w[0] >> 16));
    f[2] = bf2f((ushort_t)(w[1] & 0xffffu)); f[3] = bf2f((ushort_t)(w[1] >> 16));
}
// pack 4 floats -> 4 bf16 (8B)
__device__ __forceinline__ u32x2 pk4bf(const float* v) {
    u32x2 pk;
    pk[0] = (uint32)f2bf(v[0]) | ((uint32)f2bf(v[1]) << 16);
    pk[1] = (uint32)f2bf(v[2]) | ((uint32)f2bf(v[3]) << 16);
    return pk;
}

// fused dtype-sniff + small-vector canon: 1 launch (14 segments; bg written twice
// into the two concatenated bias buffers)
struct VecArgs { const void* s[14]; ushort_t* d[14]; int n[14]; };
__global__ void sniff_vec_kernel(const uint32* __restrict__ src, int* __restrict__ flag,
                                 VecArgs a) {
    __shared__ int cnt;
    if (threadIdx.x == 0) cnt = 0;
    __syncthreads();
    if (threadIdx.x < 64) {
        int weird = 0;
        for (int c = 0; c < 4; c++) {
            uint32 w = src[threadIdx.x * 4 + c];
            uint32 e = (w >> 7) & 0xFFu;
            weird += (e < 64u) || (e >= 192u);
        }
        if (weird) atomicAdd(&cnt, weird);
    }
    __syncthreads();
    const bool isf32 = (cnt > 32);
    if (threadIdx.x == 0) *flag = isf32 ? 1 : 0;
    const int t = threadIdx.x;
    for (int seg = 0; seg < 14; seg++) {
        const int n = a.n[seg];
        if (isf32) {
            const float* s = (const float*)a.s[seg];
            for (int i = t; i < n; i += 256) a.d[seg][i] = f2bf(s[i]);
        } else {
            const ushort_t* s = (const ushort_t*)a.s[seg];
            for (int i = t; i < n; i += 256) a.d[seg][i] = s[i];
        }
    }
}

// vectorized big canon: 8 elems/thread/iter (n % 8 == 0 for all uses)
__global__ void canon_kernel(const void* __restrict__ src, ushort_t* __restrict__ dst,
                             long n, const int* __restrict__ flag) {
    const bool isf32 = (*flag != 0);
    long i = ((long)blockIdx.x * blockDim.x + threadIdx.x) * 8;
    const long stride = (long)gridDim.x * blockDim.x * 8;
    if (isf32) {
        const float* s = (const float*)src;
        for (; i < n; i += stride) {
            const f32x4 a = *(const f32x4*)(s + i);
            const f32x4 b = *(const f32x4*)(s + i + 4);
            u32x4 o;
            o[0] = (uint32)f2bf(a[0]) | ((uint32)f2bf(a[1]) << 16);
            o[1] = (uint32)f2bf(a[2]) | ((uint32)f2bf(a[3]) << 16);
            o[2] = (uint32)f2bf(b[0]) | ((uint32)f2bf(b[1]) << 16);
            o[3] = (uint32)f2bf(b[2]) | ((uint32)f2bf(b[3]) << 16);
            *(u32x4*)(dst + i) = o;
        }
    } else {
        const ushort_t* s = (const ushort_t*)src;
        for (; i < n; i += stride)
            *(u32x4*)(dst + i) = *(const u32x4*)(s + i);
    }
}

// 6 weight transpose-canons in one launch (blockIdx.z selects slice; Wg appears
// twice: once into WpgT rows 256-511, once into WtgT rows 256-511)
struct WtArgs { const void* s[6]; ushort_t* d[6]; int R[6]; int C[6]; };
__global__ void wt_canon_all(WtArgs a, const int* __restrict__ flag) {
    const int wsel = blockIdx.z;
    const int R = a.R[wsel], C = a.C[wsel];
    const int tr = blockIdx.y, tc = blockIdx.x;
    if (tc * 32 >= C || tr * 32 >= R) return;   // block-uniform skip
    __shared__ float s[32][33];
    const bool isf32 = (*flag != 0);
    const int t = threadIdx.x;
    const int r = t >> 3, c4 = (t & 7) * 4;
    const long sbase = (long)(tr * 32 + r) * C + tc * 32 + c4;
    if (isf32) {
        const float* S = (const float*)a.s[wsel];
        const f32x4 v = *(const f32x4*)(S + sbase);
        for (int u = 0; u < 4; u++) s[r][c4 + u] = v[u];
    } else {
        const ushort_t* S = (const ushort_t*)a.s[wsel];
        for (int u = 0; u < 4; u++) s[r][c4 + u] = bf2f(S[sbase + u]);
    }
    __syncthreads();
    float tv[4];
    for (int u = 0; u < 4; u++) tv[u] = s[c4 + u][r];
    *(u32x2*)(a.d[wsel] + (long)(tc * 32 + r) * R + tr * 32 + c4) = pk4bf(tv);
}

// reduce 8 fp32 split-K partials + transposed bf16 store, both G matrices in one
// launch: zz<8 -> P1/G1T (b=zz), else P2/G2T (b=zz-8).
// out[b][n][m] = bf16( sum_{kc<8} P[(b*8+kc)*65536 + m*256 + n] )
__global__ void reduce_t2_kernel(const float* __restrict__ P1, const float* __restrict__ P2,
                                 ushort_t* __restrict__ G1T, ushort_t* __restrict__ G2T) {
    __shared__ float s[32][33];
    const int zz = blockIdx.z;
    const float* P = (zz < 8) ? P1 : P2;
    ushort_t* out  = (zz < 8) ? G1T : G2T;
    const int b = zz & 7;
    const int tm = blockIdx.y, tn = blockIdx.x;
    const int t = threadIdx.x;
    const int r = t >> 3, c4 = (t & 7) * 4;
    const float* base = P + (long)b * 8 * 65536 + (long)(tm * 32 + r) * 256 + tn * 32 + c4;
    f32x4 acc = {0.f, 0.f, 0.f, 0.f};
    for (int kc = 0; kc < 8; kc++) acc += *(const f32x4*)(base + (long)kc * 65536);
    for (int u = 0; u < 4; u++) s[r][c4 + u] = acc[u];
    __syncthreads();
    float tv[4];
    for (int u = 0; u < 4; u++) tv[u] = s[c4 + u][r];
    *(u32x2*)(out + (long)b * 65536 + (long)(tn * 32 + r) * 256 + tm * 32 + c4) = pk4bf(tv);
}

#define BM 128
#define BN 128
#define BK 32
#define LDSS 40

enum { EPI_BIAS = 0, EPI_BIASR = 1, EPI_SCALE = 2, EPI_BN = 3, EPI_PART = 4 };

// NT GEMM: C[m][n] = sum_k A[m][k] * B[n][k], both operands k-contiguous.
// Grid covers exactly (N/BN, M/BM, Z). Per-z offsets: A+=z*sA, B+=z*sB, cbase=coff+z*sC.
// EPI_PART: fp32 store (split-K partial). DUALT: also store bf16 C^T at CT (ldT).
// cnmax: C is stored only for blocks with n0 < cnmax (block-uniform; lets the merged
// convs emit C for the phi/theta halves while emitting CT for all 512 columns).
// SWAP: compute mfma(b,a) -> transposed fragment: thread holds 4 CONSECUTIVE cols
// at fixed row -> vector epilogue (f32x4 / u32x2 stores, u32x2 res/param loads).
template <int EPI, bool DYNOUT, bool DUALT, bool SWAP>
__global__ __launch_bounds__(256) void gemm_nt(
    const ushort_t* __restrict__ A, const ushort_t* __restrict__ B,
    void* __restrict__ Cv, long coff,
    int K, int lda, int ldb, int ldc, int cnmax,
    long sA, long sB, long sC,
    ushort_t* __restrict__ CT, int ldT,
    const ushort_t* __restrict__ bias,
    const ushort_t* __restrict__ gamma, const ushort_t* __restrict__ beta,
    const ushort_t* __restrict__ mean, const ushort_t* __restrict__ var,
    const ushort_t* __restrict__ res,
    float alpha, const int* __restrict__ flag)
{
    __shared__ __align__(16) ushort_t As[BM * LDSS];
    __shared__ __align__(16) ushort_t Bs[BN * LDSS];

    const bool isf32 = DYNOUT ? (*flag != 0) : false;

    const int z = blockIdx.z;
    A += (long)z * sA;
    B += (long)z * sB;
    const long cbase = coff + (long)z * sC;

    const int tid  = threadIdx.x;
    const int lane = tid & 63;
    const int w    = tid >> 6;
    const int wr   = w >> 1, wc = w & 1;
    const int lr   = lane & 15, q = lane >> 4;

    const int m0 = blockIdx.y * BM;
    const int n0 = blockIdx.x * BN;

    f32x4 acc[4][4];
#pragma unroll
    for (int i = 0; i < 4; i++)
#pragma unroll
        for (int j = 0; j < 4; j++) acc[i][j] = (f32x4){0.f, 0.f, 0.f, 0.f};

    for (int k0 = 0; k0 < K; k0 += BK) {
#pragma unroll
        for (int c = 0; c < 2; c++) {
            const int ch = tid + c * 256;
            const int r = ch >> 2, qq = ch & 3;
            *(u32x4*)(&As[r * LDSS + qq * 8]) =
                *(const u32x4*)(A + (long)(m0 + r) * lda + k0 + qq * 8);
        }
#pragma unroll
        for (int c = 0; c < 2; c++) {
            const int ch = tid + c * 256;
            const int r = ch >> 2, qq = ch & 3;
            *(u32x4*)(&Bs[r * LDSS + qq * 8]) =
                *(const u32x4*)(B + (long)(n0 + r) * ldb + k0 + qq * 8);
        }
        __syncthreads();

        bf16x8 af[4], bfr[4];
#pragma unroll
        for (int i = 0; i < 4; i++)
            af[i] = __builtin_bit_cast(bf16x8,
                *(const u32x4*)(&As[(wr * 64 + i * 16 + lr) * LDSS + q * 8]));
#pragma unroll
        for (int j = 0; j < 4; j++)
            bfr[j] = __builtin_bit_cast(bf16x8,
                *(const u32x4*)(&Bs[(wc * 64 + j * 16 + lr) * LDSS + q * 8]));
#pragma unroll
        for (int i = 0; i < 4; i++)
#pragma unroll
            for (int j = 0; j < 4; j++) {
                if constexpr (SWAP)
                    acc[i][j] = __builtin_amdgcn_mfma_f32_16x16x32_bf16(bfr[j], af[i], acc[i][j], 0, 0, 0);
                else
                    acc[i][j] = __builtin_amdgcn_mfma_f32_16x16x32_bf16(af[i], bfr[j], acc[i][j], 0, 0, 0);
            }
        __syncthreads();
    }

    if constexpr (SWAP) {
        // D layout (swapped): col=lane&15 -> m index, row=(lane>>4)*4+reg -> n index.
        // Thread holds C[m0+..+lr][n0+..+q*4 .. +3]: 4 consecutive cols -> vector stores.
#pragma unroll
        for (int j = 0; j < 4; j++) {
            const int coln = n0 + wc * 64 + j * 16 + q * 4;
            float sc4[4], sh4[4];
            if constexpr (EPI == EPI_BIAS) {
                float bb[4]; ld4bf(bias + coln, bb);
#pragma unroll
                for (int r = 0; r < 4; r++) { sc4[r] = 1.f; sh4[r] = bb[r]; }
            } else if constexpr (EPI == EPI_SCALE) {
#pragma unroll
                for (int r = 0; r < 4; r++) { sc4[r] = alpha; sh4[r] = 0.f; }
            } else if constexpr (EPI == EPI_BN) {
                float bb[4], g[4], bt[4], mn[4], vr[4];
                ld4bf(bias + coln, bb); ld4bf(gamma + coln, g); ld4bf(beta + coln, bt);
                ld4bf(mean + coln, mn); ld4bf(var + coln, vr);
#pragma unroll
                for (int r = 0; r < 4; r++) {
                    const float s = g[r] * rsqrtf(vr[r] + 1e-3f);
                    sc4[r] = s;
                    sh4[r] = s * bb[r] + bt[r] - s * mn[r];
                }
            }
#pragma unroll
            for (int i = 0; i < 4; i++) {
                const int row = m0 + wr * 64 + i * 16 + lr;
                const long off = cbase + (long)row * ldc + coln;
                float v[4];
#pragma unroll
                for (int r = 0; r < 4; r++) v[r] = acc[i][j][r];
                if constexpr (EPI == EPI_BIASR) {
                    const float bs = bf2f(bias[row]);
#pragma unroll
                    for (int r = 0; r < 4; r++) v[r] += bs;
                } else if constexpr (EPI == EPI_BN) {
                    float rs[4]; ld4bf(res + (long)row * ldc + coln, rs);
#pragma unroll
                    for (int r = 0; r < 4; r++) v[r] = sc4[r] * v[r] + sh4[r] + rs[r];
                } else if constexpr (EPI != EPI_PART) {
#pragma unroll
                    for (int r = 0; r < 4; r++) v[r] = sc4[r] * v[r] + sh4[r];
                }
                if constexpr (EPI == EPI_PART) {
                    *(f32x4*)((float*)Cv + off) = (f32x4){v[0], v[1], v[2], v[3]};
                } else if constexpr (DYNOUT) {
                    if (isf32) *(f32x4*)((float*)Cv + off) = (f32x4){v[0], v[1], v[2], v[3]};
                    else       *(u32x2*)((ushort_t*)Cv + off) = pk4bf(v);
                } else {
                    *(u32x2*)((ushort_t*)Cv + off) = pk4bf(v);
                }
            }
        }
    } else {
        // D layout: col=lane&15 -> n, row=(lane>>4)*4+reg -> m  [verified]
        const bool doC = (n0 < cnmax);
#pragma unroll
        for (int j = 0; j < 4; j++) {
            const int col = n0 + wc * 64 + j * 16 + lr;
            float bs = 0.f, sc = 1.f, sh = 0.f;
            if constexpr (EPI == EPI_BIAS || EPI == EPI_BN) bs = bf2f(bias[col]);
            if constexpr (EPI == EPI_BN) {
                const float g  = bf2f(gamma[col]);
                const float bt = bf2f(beta[col]);
                const float mn = bf2f(mean[col]);
                const float vr = bf2f(var[col]);
                sc = g * rsqrtf(vr + 1e-3f);
                sh = bt - sc * mn;
            }
#pragma unroll
            for (int i = 0; i < 4; i++) {
                const int rowbase = m0 + wr * 64 + i * 16 + q * 4;
                ushort_t tmp[4];
#pragma unroll
                for (int r = 0; r < 4; r++) {
                    const int row = rowbase + r;
                    float v = acc[i][j][r];
                    if constexpr (EPI == EPI_BIAS) v += bs;
                    else if constexpr (EPI == EPI_BIASR) v += bf2f(bias[row]);
                    else if constexpr (EPI == EPI_SCALE) v *= alpha;
                    else if constexpr (EPI == EPI_BN)
                        v = sc * (v + bs) + sh + bf2f(res[(long)row * ldc + col]);
                    const long off = cbase + (long)row * ldc + col;
                    if constexpr (EPI == EPI_PART) {
                        ((float*)Cv)[off] = v;
                    } else if constexpr (DYNOUT) {
                        if (isf32) ((float*)Cv)[off] = v;
                        else       ((ushort_t*)Cv)[off] = f2bf(v);
                    } else {
                        const ushort_t us = f2bf(v);
                        tmp[r] = us;
                        if (doC) ((ushort_t*)Cv)[off] = us;
                    }
                }
                if constexpr (DUALT) {
                    u32x2 pk;
                    pk[0] = (uint32)tmp[0] | ((uint32)tmp[1] << 16);
                    pk[1] = (uint32)tmp[2] | ((uint32)tmp[3] << 16);
                    *(u32x2*)(CT + (long)col * ldT + rowbase) = pk;
                }
            }
        }
    }
}

extern "C" void kernel_launch(void* const* d_in, const int* in_sizes, int n_in,
                              void* d_out, int out_size, void* d_ws, size_t ws_size,
                              hipStream_t stream)
{
    int* flag = (int*)d_ws;
    ushort_t* base = (ushort_t*)((char*)d_ws + 16);
    long o = 0;
    ushort_t* detect_c = base + o; o += 16777216;   // [32768][512]
    ushort_t* aim_c    = base + o; o += 4194304;    // [8192][512]
    ushort_t* WpgT = base + o; o += 262144;         // [512][512] = [WpT; WgT]
    ushort_t* WtgT = base + o; o += 262144;         // [512][512] = [WtT; WgT]
    ushort_t* WwT  = base + o; o += 131072;         // [512][256]
    ushort_t* WqT  = base + o; o += 131072;
    ushort_t* bpg_c  = base + o; o += 512;          // [bp; bg]
    ushort_t* btg_c  = base + o; o += 512;          // [bt; bg]
    ushort_t* bw_c   = base + o; o += 512;
    ushort_t* gw_c   = base + o; o += 512;
    ushort_t* betw_c = base + o; o += 512;
    ushort_t* mw_c   = base + o; o += 512;
    ushort_t* vw_c   = base + o; o += 512;
    ushort_t* bq_c   = base + o; o += 512;
    ushort_t* gq_c   = base + o; o += 512;
    ushort_t* betq_c = base + o; o += 512;
    ushort_t* mq_c   = base + o; o += 512;
    ushort_t* vq_c   = base + o; o += 512;
    ushort_t* phi    = base + o; o += 8388608;      // [32768][256]
    ushort_t* PT     = base + o; o += 16777216;     // [512][32768]: rows 0-255 phiT, 256-511 d_xT
    ushort_t* theta  = base + o; o += 2097152;      // [8192][256]
    ushort_t* TT     = base + o; o += 4194304;      // [512][8192]: rows 0-255 thetaT, 256-511 a_xT
    ushort_t* G1T    = base + o; o += 524288;       // [8][256][256]
    ushort_t* G2T    = base + o; o += 524288;
    // union region: P1,P2 (fp32, 64 slices each, lifetime ends at reduce) then na,nd
    ushort_t* U      = base + o; o += 16777216;     // 32 MiB
    float* P1 = (float*)U;                          // 64 x 65536 fp32
    float* P2 = P1 + 4194304;
    ushort_t* na = U;                               // [8192][256]
    ushort_t* nd = na + 2097152;                    // [32768][256]
    ushort_t* phiT = PT;
    ushort_t* d_xT = PT + 8388608;
    ushort_t* thetaT = TT;
    ushort_t* a_xT = TT + 2097152;

    // canon: sniff + vectors fused (bg goes into both concat bias tails)
    VecArgs va;
    const int vidx[14] = {7, 3, 5, 3, 9, 10, 11, 12, 13, 15, 16, 17, 18, 19};
    ushort_t* vdst[14] = {bpg_c, bpg_c + 256, btg_c, btg_c + 256,
                          bw_c, gw_c, betw_c, mw_c, vw_c,
                          bq_c, gq_c, betq_c, mq_c, vq_c};
    const int vn[14] = {256, 256, 256, 256, 512, 512, 512, 512, 512, 512, 512, 512, 512, 512};
    for (int i = 0; i < 14; i++) { va.s[i] = d_in[vidx[i]]; va.d[i] = vdst[i]; va.n[i] = vn[i]; }
    sniff_vec_kernel<<<1, 256, 0, stream>>>((const uint32*)d_in[0], flag, va);

    WtArgs wa;
    wa.s[0] = d_in[6];  wa.d[0] = WpgT;              wa.R[0] = 512; wa.C[0] = 256;  // Wp^T -> rows 0-255
    wa.s[1] = d_in[2];  wa.d[1] = WpgT + 256 * 512;  wa.R[1] = 512; wa.C[1] = 256;  // Wg^T -> rows 256-511
    wa.s[2] = d_in[4];  wa.d[2] = WtgT;              wa.R[2] = 512; wa.C[2] = 256;  // Wt^T
    wa.s[3] = d_in[2];  wa.d[3] = WtgT + 256 * 512;  wa.R[3] = 512; wa.C[3] = 256;  // Wg^T
    wa.s[4] = d_in[8];  wa.d[4] = WwT;               wa.R[4] = 256; wa.C[4] = 512;
    wa.s[5] = d_in[14]; wa.d[5] = WqT;               wa.R[5] = 256; wa.C[5] = 512;
    wt_canon_all<<<dim3(16, 16, 6), 256, 0, stream>>>(wa, flag);

    canon_kernel<<<2048, 256, 0, stream>>>(d_in[0], detect_c, 16777216, flag);
    canon_kernel<<<1024, 256, 0, stream>>>(d_in[1], aim_c, 4194304, flag);

    const dim3 blk(256);
    const ushort_t* np = nullptr;
    ushort_t* npm = nullptr;
    const int BIGN = 1 << 30;

    // merged detect conv: C = detect_c @ [Wp|Wg] (N=512); C-store only cols<256 (phi),
    // CT ([512][32768]) = phiT rows 0-255 + d_xT rows 256-511. One read of detect_c.
    gemm_nt<EPI_BIAS, false, true, false><<<dim3(4, 256, 1), blk, 0, stream>>>(
        detect_c, WpgT, phi, 0, 512, 512, 512, 256, 256, 0, 0, 0,
        PT, 32768, bpg_c, np, np, np, np, np, 1.f, flag);
    // merged aim conv: theta + thetaT + a_xT
    gemm_nt<EPI_BIAS, false, true, false><<<dim3(4, 64, 1), blk, 0, stream>>>(
        aim_c, WtgT, theta, 0, 512, 512, 512, 256, 256, 0, 0, 0,
        TT, 8192, btg_c, np, np, np, np, np, 1.f, flag);

    // G1 partials: z=b*8+kc, K-chunk 512 -> 256 workgroups (full GPU)
    gemm_nt<EPI_PART, false, false, true><<<dim3(2, 2, 64), blk, 0, stream>>>(
        phiT, d_xT, P1, 0, 512, 32768, 32768, 256, BIGN, 512, 512, 65536,
        npm, 0, np, np, np, np, np, np, 1.f, flag);
    // G2 partials: K-chunk 128 -> 256 workgroups
    gemm_nt<EPI_PART, false, false, true><<<dim3(2, 2, 64), blk, 0, stream>>>(
        thetaT, a_xT, P2, 0, 128, 8192, 8192, 256, BIGN, 128, 128, 65536,
        npm, 0, np, np, np, np, np, np, 1.f, flag);

    reduce_t2_kernel<<<dim3(8, 8, 16), blk, 0, stream>>>(P1, P2, G1T, G2T);

    // na = theta @ G1 / 4096  (B = G1T, NT; SWAP: u32x2 stores)
    gemm_nt<EPI_SCALE, false, false, true><<<dim3(2, 8, 8), blk, 0, stream>>>(
        theta, G1T, na, 0, 256, 256, 256, 256, BIGN, 262144, 65536, 262144,
        npm, 0, np, np, np, np, np, np, 1.f / 4096.f, flag);
    // nd = phi @ G2 / 1024
    gemm_nt<EPI_SCALE, false, false, true><<<dim3(2, 32, 8), blk, 0, stream>>>(
        phi, G2T, nd, 0, 256, 256, 256, 256, BIGN, 1048576, 65536, 1048576,
        npm, 0, np, np, np, np, np, np, 1.f / 1024.f, flag);

    // out0 = BN(na @ Ww + bw) + aim  (SWAP: f32x4 out, u32x2 res reads)
    gemm_nt<EPI_BN, true, false, true><<<dim3(4, 64, 1), blk, 0, stream>>>(
        na, WwT, d_out, 0, 256, 256, 256, 512, BIGN, 0, 0, 0,
        npm, 0, bw_c, gw_c, betw_c, mw_c, vw_c, aim_c, 1.f, flag);
    // out1 = BN(nd @ Wq + bq) + detect
    gemm_nt<EPI_BN, true, false, true><<<dim3(4, 256, 1), blk, 0, stream>>>(
        nd, WqT, d_out, 8192L * 512, 256, 256, 256, 512, BIGN, 0, 0, 0,
        npm, 0, bq_c, gq_c, betq_c, mq_c, vq_c, detect_c, 1.f, flag);
}

// Round 3
// 394.198 us; speedup vs baseline: 1.2196x; 1.0783x over previous
//
#include <hip/hip_runtime.h>

typedef unsigned short ushort_t;
typedef unsigned int uint32;
typedef __bf16 bf16x8 __attribute__((ext_vector_type(8)));
typedef float f32x4 __attribute__((ext_vector_type(4)));
typedef uint32 u32x4 __attribute__((ext_vector_type(4)));
typedef uint32 u32x2 __attribute__((ext_vector_type(2)));

typedef __attribute__((address_space(3))) uint32 as3_u32;
typedef const __attribute__((address_space(1))) uint32 as1_u32c;

// async global->LDS, 16B per lane; LDS dest = wave-uniform base + lane*16
__device__ __forceinline__ void gl_lds16(const ushort_t* g, ushort_t* l) {
    __builtin_amdgcn_global_load_lds((as1_u32c*)g, (as3_u32*)l, 16, 0, 0);
}

__device__ __forceinline__ float bf2f(ushort_t u) {
    uint32 x = ((uint32)u) << 16;
    return __builtin_bit_cast(float, x);
}
__device__ __forceinline__ ushort_t f2bf(float f) {
    uint32 x = __builtin_bit_cast(uint32, f);
    x += 0x7fffu + ((x >> 16) & 1u);   // RNE
    return (ushort_t)(x >> 16);
}
// load 4 consecutive bf16 -> 4 floats (8B vector load)
__device__ __forceinline__ void ld4bf(const ushort_t* p, float* f) {
    const u32x2 w = *(const u32x2*)p;
    f[0] = bf2f((ushort_t)(w[0] & 0xffffu)); f[1] = bf2f((ushort_t)(w[0] >> 16));
    f[2] = bf2f((ushort_t)(w[1] & 0xffffu)); f[3] = bf2f((ushort_t)(w[1] >> 16));
}
// pack 4 floats -> 4 bf16 (8B)
__device__ __forceinline__ u32x2 pk4bf(const float* v) {
    u32x2 pk;
    pk[0] = (uint32)f2bf(v[0]) | ((uint32)f2bf(v[1]) << 16);
    pk[1] = (uint32)f2bf(v[2]) | ((uint32)f2bf(v[3]) << 16);
    return pk;
}

// fused dtype-sniff + small-vector canon: 1 launch (14 segments; bg written twice
// into the two concatenated bias buffers)
struct VecArgs { const void* s[14]; ushort_t* d[14]; int n[14]; };
__global__ void sniff_vec_kernel(const uint32* __restrict__ src, int* __restrict__ flag,
                                 VecArgs a) {
    __shared__ int cnt;
    if (threadIdx.x == 0) cnt = 0;
    __syncthreads();
    if (threadIdx.x < 64) {
        int weird = 0;
        for (int c = 0; c < 4; c++) {
            uint32 w = src[threadIdx.x * 4 + c];
            uint32 e = (w >> 7) & 0xFFu;
            weird += (e < 64u) || (e >= 192u);
        }
        if (weird) atomicAdd(&cnt, weird);
    }
    __syncthreads();
    const bool isf32 = (cnt > 32);
    if (threadIdx.x == 0) *flag = isf32 ? 1 : 0;
    const int t = threadIdx.x;
    for (int seg = 0; seg < 14; seg++) {
        const int n = a.n[seg];
        if (isf32) {
            const float* s = (const float*)a.s[seg];
            for (int i = t; i < n; i += 256) a.d[seg][i] = f2bf(s[i]);
        } else {
            const ushort_t* s = (const ushort_t*)a.s[seg];
            for (int i = t; i < n; i += 256) a.d[seg][i] = s[i];
        }
    }
}

// vectorized big canon: 8 elems/thread/iter (n % 8 == 0 for all uses)
__global__ void canon_kernel(const void* __restrict__ src, ushort_t* __restrict__ dst,
                             long n, const int* __restrict__ flag) {
    const bool isf32 = (*flag != 0);
    long i = ((long)blockIdx.x * blockDim.x + threadIdx.x) * 8;
    const long stride = (long)gridDim.x * blockDim.x * 8;
    if (isf32) {
        const float* s = (const float*)src;
        for (; i < n; i += stride) {
            const f32x4 a = *(const f32x4*)(s + i);
            const f32x4 b = *(const f32x4*)(s + i + 4);
            u32x4 o;
            o[0] = (uint32)f2bf(a[0]) | ((uint32)f2bf(a[1]) << 16);
            o[1] = (uint32)f2bf(a[2]) | ((uint32)f2bf(a[3]) << 16);
            o[2] = (uint32)f2bf(b[0]) | ((uint32)f2bf(b[1]) << 16);
            o[3] = (uint32)f2bf(b[2]) | ((uint32)f2bf(b[3]) << 16);
            *(u32x4*)(dst + i) = o;
        }
    } else {
        const ushort_t* s = (const ushort_t*)src;
        for (; i < n; i += stride)
            *(u32x4*)(dst + i) = *(const u32x4*)(s + i);
    }
}

// 6 weight transpose-canons in one launch (blockIdx.z selects slice; Wg appears
// twice: once into WpgT rows 256-511, once into WtgT rows 256-511)
struct WtArgs { const void* s[6]; ushort_t* d[6]; int R[6]; int C[6]; };
__global__ void wt_canon_all(WtArgs a, const int* __restrict__ flag) {
    const int wsel = blockIdx.z;
    const int R = a.R[wsel], C = a.C[wsel];
    const int tr = blockIdx.y, tc = blockIdx.x;
    if (tc * 32 >= C || tr * 32 >= R) return;   // block-uniform skip
    __shared__ float s[32][33];
    const bool isf32 = (*flag != 0);
    const int t = threadIdx.x;
    const int r = t >> 3, c4 = (t & 7) * 4;
    const long sbase = (long)(tr * 32 + r) * C + tc * 32 + c4;
    if (isf32) {
        const float* S = (const float*)a.s[wsel];
        const f32x4 v = *(const f32x4*)(S + sbase);
        for (int u = 0; u < 4; u++) s[r][c4 + u] = v[u];
    } else {
        const ushort_t* S = (const ushort_t*)a.s[wsel];
        for (int u = 0; u < 4; u++) s[r][c4 + u] = bf2f(S[sbase + u]);
    }
    __syncthreads();
    float tv[4];
    for (int u = 0; u < 4; u++) tv[u] = s[c4 + u][r];
    *(u32x2*)(a.d[wsel] + (long)(tc * 32 + r) * R + tr * 32 + c4) = pk4bf(tv);
}

// reduce 8 fp32 split-K partials + transposed bf16 store, both G matrices in one
// launch: zz<8 -> P1/G1T (b=zz), else P2/G2T (b=zz-8).
__global__ void reduce_t2_kernel(const float* __restrict__ P1, const float* __restrict__ P2,
                                 ushort_t* __restrict__ G1T, ushort_t* __restrict__ G2T) {
    __shared__ float s[32][33];
    const int zz = blockIdx.z;
    const float* P = (zz < 8) ? P1 : P2;
    ushort_t* out  = (zz < 8) ? G1T : G2T;
    const int b = zz & 7;
    const int tm = blockIdx.y, tn = blockIdx.x;
    const int t = threadIdx.x;
    const int r = t >> 3, c4 = (t & 7) * 4;
    const float* base = P + (long)b * 8 * 65536 + (long)(tm * 32 + r) * 256 + tn * 32 + c4;
    f32x4 acc = {0.f, 0.f, 0.f, 0.f};
    for (int kc = 0; kc < 8; kc++) acc += *(const f32x4*)(base + (long)kc * 65536);
    for (int u = 0; u < 4; u++) s[r][c4 + u] = acc[u];
    __syncthreads();
    float tv[4];
    for (int u = 0; u < 4; u++) tv[u] = s[c4 + u][r];
    *(u32x2*)(out + (long)b * 65536 + (long)(tn * 32 + r) * 256 + tm * 32 + c4) = pk4bf(tv);
}

#define BM 128
#define BN 128
#define BK 32

enum { EPI_BIAS = 0, EPI_BIASR = 1, EPI_SCALE = 2, EPI_BN = 3, EPI_PART = 4 };

// NT GEMM: C[m][n] = sum_k A[m][k] * B[n][k], both operands k-contiguous.
// global_load_lds staging (16B/lane) into linear [128][32] LDS tiles; source unit
// index pre-swizzled (u ^= (row>>1)&3) so the XOR-swizzled ds_read_b128 fragment
// reads are 2-way-bank-aliased (free). XCD-bijective block swizzle (nwg%8==0 for
// all launches). EPI_PART: fp32 store. DUALT: also store bf16 C^T at CT (ldT).
// cnmax: C stored only for blocks with n0 < cnmax (merged convs).
template <int EPI, bool DYNOUT, bool DUALT, bool SWAP>
__global__ __launch_bounds__(256) void gemm_nt(
    const ushort_t* __restrict__ A, const ushort_t* __restrict__ B,
    void* __restrict__ Cv, long coff,
    int K, int lda, int ldb, int ldc, int cnmax,
    long sA, long sB, long sC,
    ushort_t* __restrict__ CT, int ldT,
    const ushort_t* __restrict__ bias,
    const ushort_t* __restrict__ gamma, const ushort_t* __restrict__ beta,
    const ushort_t* __restrict__ mean, const ushort_t* __restrict__ var,
    const ushort_t* __restrict__ res,
    float alpha, const int* __restrict__ flag)
{
    __shared__ __align__(16) ushort_t As[BM * BK];
    __shared__ __align__(16) ushort_t Bs[BN * BK];

    const bool isf32 = DYNOUT ? (*flag != 0) : false;

    // XCD-aware bijective swizzle of the flattened block id (requires nwg%8==0)
    const uint32 gx = gridDim.x, gy = gridDim.y;
    const uint32 nwg = gx * gy * gridDim.z;
    const uint32 lid = blockIdx.x + gx * (blockIdx.y + gy * blockIdx.z);
    const uint32 swz = (lid & 7u) * (nwg >> 3) + (lid >> 3);
    const uint32 bx = swz % gx, t1 = swz / gx;
    const uint32 by = t1 % gy, bz = t1 / gy;

    A += (long)bz * sA;
    B += (long)bz * sB;
    const long cbase = coff + (long)bz * sC;

    const int tid  = threadIdx.x;
    const int lane = tid & 63;
    const int w    = tid >> 6;
    const int wr   = w >> 1, wc = w & 1;
    const int lr   = lane & 15, q = lane >> 4;

    const int m0 = by * BM;
    const int n0 = bx * BN;

    // staging geometry: wave w covers rows [w*32, w*32+31] via two 1KB segments
    const int lrow = lane >> 2, lu = lane & 3;
    const int us = (lu ^ ((lrow >> 1) & 3)) * 8;          // source-side swizzle
    const int ra0 = w * 32 + lrow, ra1 = w * 32 + 16 + lrow;
    const ushort_t* Ar0 = A + (long)(m0 + ra0) * lda + us;
    const ushort_t* Ar1 = A + (long)(m0 + ra1) * lda + us;
    const ushort_t* Br0 = B + (long)(n0 + ra0) * ldb + us;
    const ushort_t* Br1 = B + (long)(n0 + ra1) * ldb + us;
    ushort_t* sA0 = &As[(w * 2 + 0) * 512];
    ushort_t* sA1 = &As[(w * 2 + 1) * 512];
    ushort_t* sB0 = &Bs[(w * 2 + 0) * 512];
    ushort_t* sB1 = &Bs[(w * 2 + 1) * 512];

    const int swq = (q ^ ((lr >> 1) & 3)) * 8;            // read-side swizzle

    f32x4 acc[4][4];
#pragma unroll
    for (int i = 0; i < 4; i++)
#pragma unroll
        for (int j = 0; j < 4; j++) acc[i][j] = (f32x4){0.f, 0.f, 0.f, 0.f};

    for (int k0 = 0; k0 < K; k0 += BK) {
        gl_lds16(Ar0 + k0, sA0);
        gl_lds16(Ar1 + k0, sA1);
        gl_lds16(Br0 + k0, sB0);
        gl_lds16(Br1 + k0, sB1);
        __syncthreads();

        bf16x8 af[4], bfr[4];
#pragma unroll
        for (int i = 0; i < 4; i++)
            af[i] = __builtin_bit_cast(bf16x8,
                *(const u32x4*)(&As[(wr * 64 + i * 16 + lr) * BK + swq]));
#pragma unroll
        for (int j = 0; j < 4; j++)
            bfr[j] = __builtin_bit_cast(bf16x8,
                *(const u32x4*)(&Bs[(wc * 64 + j * 16 + lr) * BK + swq]));
#pragma unroll
        for (int i = 0; i < 4; i++)
#pragma unroll
            for (int j = 0; j < 4; j++) {
                if constexpr (SWAP)
                    acc[i][j] = __builtin_amdgcn_mfma_f32_16x16x32_bf16(bfr[j], af[i], acc[i][j], 0, 0, 0);
                else
                    acc[i][j] = __builtin_amdgcn_mfma_f32_16x16x32_bf16(af[i], bfr[j], acc[i][j], 0, 0, 0);
            }
        __syncthreads();
    }

    if constexpr (SWAP) {
        // D layout (swapped): thread holds C[m0+..+lr][coln .. coln+3] -> vector stores
#pragma unroll
        for (int j = 0; j < 4; j++) {
            const int coln = n0 + wc * 64 + j * 16 + q * 4;
            float sc4[4], sh4[4];
            if constexpr (EPI == EPI_BIAS) {
                float bb[4]; ld4bf(bias + coln, bb);
#pragma unroll
                for (int r = 0; r < 4; r++) { sc4[r] = 1.f; sh4[r] = bb[r]; }
            } else if constexpr (EPI == EPI_SCALE) {
#pragma unroll
                for (int r = 0; r < 4; r++) { sc4[r] = alpha; sh4[r] = 0.f; }
            } else if constexpr (EPI == EPI_BN) {
                float bb[4], g[4], bt[4], mn[4], vr[4];
                ld4bf(bias + coln, bb); ld4bf(gamma + coln, g); ld4bf(beta + coln, bt);
                ld4bf(mean + coln, mn); ld4bf(var + coln, vr);
#pragma unroll
                for (int r = 0; r < 4; r++) {
                    const float s = g[r] * rsqrtf(vr[r] + 1e-3f);
                    sc4[r] = s;
                    sh4[r] = s * bb[r] + bt[r] - s * mn[r];
                }
            }
#pragma unroll
            for (int i = 0; i < 4; i++) {
                const int row = m0 + wr * 64 + i * 16 + lr;
                const long off = cbase + (long)row * ldc + coln;
                float v[4];
#pragma unroll
                for (int r = 0; r < 4; r++) v[r] = acc[i][j][r];
                if constexpr (EPI == EPI_BIASR) {
                    const float bs = bf2f(bias[row]);
#pragma unroll
                    for (int r = 0; r < 4; r++) v[r] += bs;
                } else if constexpr (EPI == EPI_BN) {
                    float rs[4]; ld4bf(res + (long)row * ldc + coln, rs);
#pragma unroll
                    for (int r = 0; r < 4; r++) v[r] = sc4[r] * v[r] + sh4[r] + rs[r];
                } else if constexpr (EPI != EPI_PART) {
#pragma unroll
                    for (int r = 0; r < 4; r++) v[r] = sc4[r] * v[r] + sh4[r];
                }
                if constexpr (EPI == EPI_PART) {
                    *(f32x4*)((float*)Cv + off) = (f32x4){v[0], v[1], v[2], v[3]};
                } else if constexpr (DYNOUT) {
                    if (isf32) *(f32x4*)((float*)Cv + off) = (f32x4){v[0], v[1], v[2], v[3]};
                    else       *(u32x2*)((ushort_t*)Cv + off) = pk4bf(v);
                } else {
                    *(u32x2*)((ushort_t*)Cv + off) = pk4bf(v);
                }
            }
        }
    } else {
        // D layout: col=lane&15 -> n, row=(lane>>4)*4+reg -> m  [verified]
        const bool doC = ((int)n0 < cnmax);
#pragma unroll
        for (int j = 0; j < 4; j++) {
            const int col = n0 + wc * 64 + j * 16 + lr;
            float bs = 0.f, sc = 1.f, sh = 0.f;
            if constexpr (EPI == EPI_BIAS || EPI == EPI_BN) bs = bf2f(bias[col]);
            if constexpr (EPI == EPI_BN) {
                const float g  = bf2f(gamma[col]);
                const float bt = bf2f(beta[col]);
                const float mn = bf2f(mean[col]);
                const float vr = bf2f(var[col]);
                sc = g * rsqrtf(vr + 1e-3f);
                sh = bt - sc * mn;
            }
#pragma unroll
            for (int i = 0; i < 4; i++) {
                const int rowbase = m0 + wr * 64 + i * 16 + q * 4;
                ushort_t tmp[4];
#pragma unroll
                for (int r = 0; r < 4; r++) {
                    const int row = rowbase + r;
                    float v = acc[i][j][r];
                    if constexpr (EPI == EPI_BIAS) v += bs;
                    else if constexpr (EPI == EPI_BIASR) v += bf2f(bias[row]);
                    else if constexpr (EPI == EPI_SCALE) v *= alpha;
                    else if constexpr (EPI == EPI_BN)
                        v = sc * (v + bs) + sh + bf2f(res[(long)row * ldc + col]);
                    const long off = cbase + (long)row * ldc + col;
                    if constexpr (EPI == EPI_PART) {
                        ((float*)Cv)[off] = v;
                    } else if constexpr (DYNOUT) {
                        if (isf32) ((float*)Cv)[off] = v;
                        else       ((ushort_t*)Cv)[off] = f2bf(v);
                    } else {
                        const ushort_t us2 = f2bf(v);
                        tmp[r] = us2;
                        if (doC) ((ushort_t*)Cv)[off] = us2;
                    }
                }
                if constexpr (DUALT) {
                    u32x2 pk;
                    pk[0] = (uint32)tmp[0] | ((uint32)tmp[1] << 16);
                    pk[1] = (uint32)tmp[2] | ((uint32)tmp[3] << 16);
                    *(u32x2*)(CT + (long)col * ldT + rowbase) = pk;
                }
            }
        }
    }
}

extern "C" void kernel_launch(void* const* d_in, const int* in_sizes, int n_in,
                              void* d_out, int out_size, void* d_ws, size_t ws_size,
                              hipStream_t stream)
{
    int* flag = (int*)d_ws;
    ushort_t* base = (ushort_t*)((char*)d_ws + 16);
    long o = 0;
    ushort_t* detect_c = base + o; o += 16777216;   // [32768][512]
    ushort_t* aim_c    = base + o; o += 4194304;    // [8192][512]
    ushort_t* WpgT = base + o; o += 262144;         // [512][512] = [WpT; WgT]
    ushort_t* WtgT = base + o; o += 262144;         // [512][512] = [WtT; WgT]
    ushort_t* WwT  = base + o; o += 131072;         // [512][256]
    ushort_t* WqT  = base + o; o += 131072;
    ushort_t* bpg_c  = base + o; o += 512;          // [bp; bg]
    ushort_t* btg_c  = base + o; o += 512;          // [bt; bg]
    ushort_t* bw_c   = base + o; o += 512;
    ushort_t* gw_c   = base + o; o += 512;
    ushort_t* betw_c = base + o; o += 512;
    ushort_t* mw_c   = base + o; o += 512;
    ushort_t* vw_c   = base + o; o += 512;
    ushort_t* bq_c   = base + o; o += 512;
    ushort_t* gq_c   = base + o; o += 512;
    ushort_t* betq_c = base + o; o += 512;
    ushort_t* mq_c   = base + o; o += 512;
    ushort_t* vq_c   = base + o; o += 512;
    ushort_t* phi    = base + o; o += 8388608;      // [32768][256]
    ushort_t* PT     = base + o; o += 16777216;     // [512][32768]: rows 0-255 phiT, 256-511 d_xT
    ushort_t* theta  = base + o; o += 2097152;      // [8192][256]
    ushort_t* TT     = base + o; o += 4194304;      // [512][8192]: rows 0-255 thetaT, 256-511 a_xT
    ushort_t* G1T    = base + o; o += 524288;       // [8][256][256]
    ushort_t* G2T    = base + o; o += 524288;
    // union region: P1,P2 (fp32, 64 slices each, lifetime ends at reduce) then na,nd
    ushort_t* U      = base + o; o += 16777216;     // 32 MiB
    float* P1 = (float*)U;                          // 64 x 65536 fp32
    float* P2 = P1 + 4194304;
    ushort_t* na = U;                               // [8192][256]
    ushort_t* nd = na + 2097152;                    // [32768][256]
    ushort_t* phiT = PT;
    ushort_t* d_xT = PT + 8388608;
    ushort_t* thetaT = TT;
    ushort_t* a_xT = TT + 2097152;

    // canon: sniff + vectors fused (bg goes into both concat bias tails)
    VecArgs va;
    const int vidx[14] = {7, 3, 5, 3, 9, 10, 11, 12, 13, 15, 16, 17, 18, 19};
    ushort_t* vdst[14] = {bpg_c, bpg_c + 256, btg_c, btg_c + 256,
                          bw_c, gw_c, betw_c, mw_c, vw_c,
                          bq_c, gq_c, betq_c, mq_c, vq_c};
    const int vn[14] = {256, 256, 256, 256, 512, 512, 512, 512, 512, 512, 512, 512, 512, 512};
    for (int i = 0; i < 14; i++) { va.s[i] = d_in[vidx[i]]; va.d[i] = vdst[i]; va.n[i] = vn[i]; }
    sniff_vec_kernel<<<1, 256, 0, stream>>>((const uint32*)d_in[0], flag, va);

    WtArgs wa;
    wa.s[0] = d_in[6];  wa.d[0] = WpgT;              wa.R[0] = 512; wa.C[0] = 256;  // Wp^T -> rows 0-255
    wa.s[1] = d_in[2];  wa.d[1] = WpgT + 256 * 512;  wa.R[1] = 512; wa.C[1] = 256;  // Wg^T -> rows 256-511
    wa.s[2] = d_in[4];  wa.d[2] = WtgT;              wa.R[2] = 512; wa.C[2] = 256;  // Wt^T
    wa.s[3] = d_in[2];  wa.d[3] = WtgT + 256 * 512;  wa.R[3] = 512; wa.C[3] = 256;  // Wg^T
    wa.s[4] = d_in[8];  wa.d[4] = WwT;               wa.R[4] = 256; wa.C[4] = 512;
    wa.s[5] = d_in[14]; wa.d[5] = WqT;               wa.R[5] = 256; wa.C[5] = 512;
    wt_canon_all<<<dim3(16, 16, 6), 256, 0, stream>>>(wa, flag);

    canon_kernel<<<2048, 256, 0, stream>>>(d_in[0], detect_c, 16777216, flag);
    canon_kernel<<<1024, 256, 0, stream>>>(d_in[1], aim_c, 4194304, flag);

    const dim3 blk(256);
    const ushort_t* np = nullptr;
    ushort_t* npm = nullptr;
    const int BIGN = 1 << 30;

    // merged detect conv: C = detect_c @ [Wp|Wg] (N=512); C-store only cols<256 (phi),
    // CT ([512][32768]) = phiT rows 0-255 + d_xT rows 256-511. One read of detect_c.
    gemm_nt<EPI_BIAS, false, true, false><<<dim3(4, 256, 1), blk, 0, stream>>>(
        detect_c, WpgT, phi, 0, 512, 512, 512, 256, 256, 0, 0, 0,
        PT, 32768, bpg_c, np, np, np, np, np, 1.f, flag);
    // merged aim conv: theta + thetaT + a_xT
    gemm_nt<EPI_BIAS, false, true, false><<<dim3(4, 64, 1), blk, 0, stream>>>(
        aim_c, WtgT, theta, 0, 512, 512, 512, 256, 256, 0, 0, 0,
        TT, 8192, btg_c, np, np, np, np, np, 1.f, flag);

    // G1 partials: z=b*8+kc, K-chunk 512 -> 256 workgroups (full GPU)
    gemm_nt<EPI_PART, false, false, true><<<dim3(2, 2, 64), blk, 0, stream>>>(
        phiT, d_xT, P1, 0, 512, 32768, 32768, 256, BIGN, 512, 512, 65536,
        npm, 0, np, np, np, np, np, np, 1.f, flag);
    // G2 partials: K-chunk 128 -> 256 workgroups
    gemm_nt<EPI_PART, false, false, true><<<dim3(2, 2, 64), blk, 0, stream>>>(
        thetaT, a_xT, P2, 0, 128, 8192, 8192, 256, BIGN, 128, 128, 65536,
        npm, 0, np, np, np, np, np, np, 1.f, flag);

    reduce_t2_kernel<<<dim3(8, 8, 16), blk, 0, stream>>>(P1, P2, G1T, G2T);

    // na = theta @ G1 / 4096  (B = G1T, NT; SWAP: u32x2 stores)
    gemm_nt<EPI_SCALE, false, false, true><<<dim3(2, 8, 8), blk, 0, stream>>>(
        theta, G1T, na, 0, 256, 256, 256, 256, BIGN, 262144, 65536, 262144,
        npm, 0, np, np, np, np, np, np, 1.f / 4096.f, flag);
    // nd = phi @ G2 / 1024
    gemm_nt<EPI_SCALE, false, false, true><<<dim3(2, 32, 8), blk, 0, stream>>>(
        phi, G2T, nd, 0, 256, 256, 256, 256, BIGN, 1048576, 65536, 1048576,
        npm, 0, np, np, np, np, np, np, 1.f / 1024.f, flag);

    // out0 = BN(na @ Ww + bw) + aim  (SWAP: f32x4 out, u32x2 res reads)
    gemm_nt<EPI_BN, true, false, true><<<dim3(4, 64, 1), blk, 0, stream>>>(
        na, WwT, d_out, 0, 256, 256, 256, 512, BIGN, 0, 0, 0,
        npm, 0, bw_c, gw_c, betw_c, mw_c, vw_c, aim_c, 1.f, flag);
    // out1 = BN(nd @ Wq + bq) + detect
    gemm_nt<EPI_BN, true, false, true><<<dim3(4, 256, 1), blk, 0, stream>>>(
        nd, WqT, d_out, 8192L * 512, 256, 256, 256, 512, BIGN, 0, 0, 0,
        npm, 0, bq_c, gq_c, betq_c, mq_c, vq_c, detect_c, 1.f, flag);
}

// Round 4
// 368.484 us; speedup vs baseline: 1.3048x; 1.0698x over previous
//
#include <hip/hip_runtime.h>

typedef unsigned short ushort_t;
typedef unsigned int uint32;
typedef __bf16 bf16x8 __attribute__((ext_vector_type(8)));
typedef float f32x4 __attribute__((ext_vector_type(4)));
typedef uint32 u32x4 __attribute__((ext_vector_type(4)));
typedef uint32 u32x2 __attribute__((ext_vector_type(2)));

typedef __attribute__((address_space(3))) uint32 as3_u32;
typedef const __attribute__((address_space(1))) uint32 as1_u32c;

// async global->LDS, 16B per lane; LDS dest = wave-uniform base + lane*16
__device__ __forceinline__ void gl_lds16(const ushort_t* g, ushort_t* l) {
    __builtin_amdgcn_global_load_lds((as1_u32c*)g, (as3_u32*)l, 16, 0, 0);
}

__device__ __forceinline__ float bf2f(ushort_t u) {
    uint32 x = ((uint32)u) << 16;
    return __builtin_bit_cast(float, x);
}
__device__ __forceinline__ ushort_t f2bf(float f) {
    uint32 x = __builtin_bit_cast(uint32, f);
    x += 0x7fffu + ((x >> 16) & 1u);   // RNE
    return (ushort_t)(x >> 16);
}
// load 4 consecutive bf16 -> 4 floats (8B vector load)
__device__ __forceinline__ void ld4bf(const ushort_t* p, float* f) {
    const u32x2 w = *(const u32x2*)p;
    f[0] = bf2f((ushort_t)(w[0] & 0xffffu)); f[1] = bf2f((ushort_t)(w[0] >> 16));
    f[2] = bf2f((ushort_t)(w[1] & 0xffffu)); f[3] = bf2f((ushort_t)(w[1] >> 16));
}
// pack 4 floats -> 4 bf16 (8B)
__device__ __forceinline__ u32x2 pk4bf(const float* v) {
    u32x2 pk;
    pk[0] = (uint32)f2bf(v[0]) | ((uint32)f2bf(v[1]) << 16);
    pk[1] = (uint32)f2bf(v[2]) | ((uint32)f2bf(v[3]) << 16);
    return pk;
}

// fused dtype-sniff + small-vector canon: 1 launch (14 segments; bg written twice
// into the two concatenated bias buffers)
struct VecArgs { const void* s[14]; ushort_t* d[14]; int n[14]; };
__global__ void sniff_vec_kernel(const uint32* __restrict__ src, int* __restrict__ flag,
                                 VecArgs a) {
    __shared__ int cnt;
    if (threadIdx.x == 0) cnt = 0;
    __syncthreads();
    if (threadIdx.x < 64) {
        int weird = 0;
        for (int c = 0; c < 4; c++) {
            uint32 w = src[threadIdx.x * 4 + c];
            uint32 e = (w >> 7) & 0xFFu;
            weird += (e < 64u) || (e >= 192u);
        }
        if (weird) atomicAdd(&cnt, weird);
    }
    __syncthreads();
    const bool isf32 = (cnt > 32);
    if (threadIdx.x == 0) *flag = isf32 ? 1 : 0;
    const int t = threadIdx.x;
    for (int seg = 0; seg < 14; seg++) {
        const int n = a.n[seg];
        if (isf32) {
            const float* s = (const float*)a.s[seg];
            for (int i = t; i < n; i += 256) a.d[seg][i] = f2bf(s[i]);
        } else {
            const ushort_t* s = (const ushort_t*)a.s[seg];
            for (int i = t; i < n; i += 256) a.d[seg][i] = s[i];
        }
    }
}

// all remaining canon work in ONE launch:
//   blocks [0,2048)      : detect activation canon (16.7M elems, vectorized x8)
//   blocks [2048,3072)   : aim activation canon (4.2M elems)
//   blocks [3072,4608)   : 6 weight transpose slices (256 blocks each, guarded)
struct WtArgs { const void* s[6]; ushort_t* d[6]; int R[6]; int C[6]; };
__global__ void canon_all(const void* __restrict__ dsrc, ushort_t* __restrict__ ddst,
                          const void* __restrict__ asrc, ushort_t* __restrict__ adst,
                          WtArgs wa, const int* __restrict__ flag) {
    const bool isf32 = (*flag != 0);
    const int b = blockIdx.x;
    if (b < 3072) {
        const void* src; ushort_t* dst; long n; int b0, nb;
        if (b < 2048) { src = dsrc; dst = ddst; n = 16777216; b0 = b; nb = 2048; }
        else          { src = asrc; dst = adst; n = 4194304;  b0 = b - 2048; nb = 1024; }
        long i = ((long)b0 * 256 + threadIdx.x) * 8;
        const long stride = (long)nb * 256 * 8;
        if (isf32) {
            const float* s = (const float*)src;
            for (; i < n; i += stride) {
                const f32x4 a = *(const f32x4*)(s + i);
                const f32x4 c = *(const f32x4*)(s + i + 4);
                u32x4 o;
                o[0] = (uint32)f2bf(a[0]) | ((uint32)f2bf(a[1]) << 16);
                o[1] = (uint32)f2bf(a[2]) | ((uint32)f2bf(a[3]) << 16);
                o[2] = (uint32)f2bf(c[0]) | ((uint32)f2bf(c[1]) << 16);
                o[3] = (uint32)f2bf(c[2]) | ((uint32)f2bf(c[3]) << 16);
                *(u32x4*)(dst + i) = o;
            }
        } else {
            const ushort_t* s = (const ushort_t*)src;
            for (; i < n; i += stride)
                *(u32x4*)(dst + i) = *(const u32x4*)(s + i);
        }
    } else {
        const int local = b - 3072;
        const int wsel = local >> 8;
        const int rem = local & 255;
        const int tr = rem >> 4, tc = rem & 15;
        const int R = wa.R[wsel], C = wa.C[wsel];
        if (tc * 32 >= C || tr * 32 >= R) return;   // block-uniform skip
        __shared__ float s[32][33];
        const int t = threadIdx.x;
        const int r = t >> 3, c4 = (t & 7) * 4;
        const long sbase = (long)(tr * 32 + r) * C + tc * 32 + c4;
        if (isf32) {
            const float* S = (const float*)wa.s[wsel];
            const f32x4 v = *(const f32x4*)(S + sbase);
            for (int u = 0; u < 4; u++) s[r][c4 + u] = v[u];
        } else {
            const ushort_t* S = (const ushort_t*)wa.s[wsel];
            for (int u = 0; u < 4; u++) s[r][c4 + u] = bf2f(S[sbase + u]);
        }
        __syncthreads();
        float tv[4];
        for (int u = 0; u < 4; u++) tv[u] = s[c4 + u][r];
        *(u32x2*)(wa.d[wsel] + (long)(tc * 32 + r) * R + tr * 32 + c4) = pk4bf(tv);
    }
}

// reduce 8 fp32 split-K partials + transposed bf16 store, both G matrices in one
// launch: zz<8 -> P1/G1T (b=zz), else P2/G2T (b=zz-8).
__global__ void reduce_t2_kernel(const float* __restrict__ P1, const float* __restrict__ P2,
                                 ushort_t* __restrict__ G1T, ushort_t* __restrict__ G2T) {
    __shared__ float s[32][33];
    const int zz = blockIdx.z;
    const float* P = (zz < 8) ? P1 : P2;
    ushort_t* out  = (zz < 8) ? G1T : G2T;
    const int b = zz & 7;
    const int tm = blockIdx.y, tn = blockIdx.x;
    const int t = threadIdx.x;
    const int r = t >> 3, c4 = (t & 7) * 4;
    const float* base = P + (long)b * 8 * 65536 + (long)(tm * 32 + r) * 256 + tn * 32 + c4;
    f32x4 acc = {0.f, 0.f, 0.f, 0.f};
    for (int kc = 0; kc < 8; kc++) acc += *(const f32x4*)(base + (long)kc * 65536);
    for (int u = 0; u < 4; u++) s[r][c4 + u] = acc[u];
    __syncthreads();
    float tv[4];
    for (int u = 0; u < 4; u++) tv[u] = s[c4 + u][r];
    *(u32x2*)(out + (long)b * 65536 + (long)(tn * 32 + r) * 256 + tm * 32 + c4) = pk4bf(tv);
}

#define BM 128
#define BN 128
#define BK 32
#define BIGN (1 << 30)

enum { EPI_BIAS = 0, EPI_BIASR = 1, EPI_SCALE = 2, EPI_BN = 3, EPI_PART = 4 };

// per-GEMM parameter set (two per launch; selected block-uniformly by y/z split)
struct GP {
    const ushort_t* A; const ushort_t* B; void* Cv; ushort_t* CT;
    const ushort_t* bias; const ushort_t* gamma; const ushort_t* beta;
    const ushort_t* mean; const ushort_t* var; const ushort_t* res;
    long coff, sA, sB, sC;
    int K, lda, ldb, ldc, cnmax, ldT;
    float alpha;
};
struct GP2 { GP g[2]; };

// NT GEMM: C[m][n] = sum_k A[m][k] * B[n][k], both operands k-contiguous.
// global_load_lds staging (16B/lane) into linear [128][32] LDS tiles; source unit
// index pre-swizzled (u ^= (row>>1)&3) so the XOR-swizzled ds_read_b128 fragment
// reads are 2-way-bank-aliased (free). XCD-bijective block swizzle (nwg%8==0 for
// all launches). Two fused sub-GEMMs per launch: after swizzle decode, blocks with
// by>=ysplit or bz>=zsplit run parameter set 1 (with by/bz rebased).
template <int EPI, bool DYNOUT, bool DUALT, bool SWAP>
__global__ __launch_bounds__(256) void gemm_nt(GP2 ga, int ysplit, int zsplit,
                                               const int* __restrict__ flag)
{
    __shared__ __align__(16) ushort_t As[BM * BK];
    __shared__ __align__(16) ushort_t Bs[BN * BK];

    const bool isf32 = DYNOUT ? (*flag != 0) : false;

    // XCD-aware bijective swizzle of the flattened block id (requires nwg%8==0)
    const uint32 gx = gridDim.x, gy = gridDim.y;
    const uint32 nwg = gx * gy * gridDim.z;
    const uint32 lid = blockIdx.x + gx * (blockIdx.y + gy * blockIdx.z);
    const uint32 swz = (lid & 7u) * (nwg >> 3) + (lid >> 3);
    const uint32 bx = swz % gx, t1 = swz / gx;
    int by = (int)(t1 % gy), bz = (int)(t1 / gy);

    int sel = 0;
    if (by >= ysplit) { by -= ysplit; sel = 1; }
    if (bz >= zsplit) { bz -= zsplit; sel = 1; }
    const GP& p = ga.g[sel];

    const ushort_t* A = p.A + (long)bz * p.sA;
    const ushort_t* B = p.B + (long)bz * p.sB;
    const long cbase = p.coff + (long)bz * p.sC;
    const int lda = p.lda, ldb = p.ldb, ldc = p.ldc, K = p.K;

    const int tid  = threadIdx.x;
    const int lane = tid & 63;
    const int w    = tid >> 6;
    const int wr   = w >> 1, wc = w & 1;
    const int lr   = lane & 15, q = lane >> 4;

    const int m0 = by * BM;
    const int n0 = bx * BN;

    // staging geometry: wave w covers rows [w*32, w*32+31] via two 1KB segments
    const int lrow = lane >> 2, lu = lane & 3;
    const int us = (lu ^ ((lrow >> 1) & 3)) * 8;          // source-side swizzle
    const int ra0 = w * 32 + lrow, ra1 = w * 32 + 16 + lrow;
    const ushort_t* Ar0 = A + (long)(m0 + ra0) * lda + us;
    const ushort_t* Ar1 = A + (long)(m0 + ra1) * lda + us;
    const ushort_t* Br0 = B + (long)(n0 + ra0) * ldb + us;
    const ushort_t* Br1 = B + (long)(n0 + ra1) * ldb + us;
    ushort_t* sA0 = &As[(w * 2 + 0) * 512];
    ushort_t* sA1 = &As[(w * 2 + 1) * 512];
    ushort_t* sB0 = &Bs[(w * 2 + 0) * 512];
    ushort_t* sB1 = &Bs[(w * 2 + 1) * 512];

    const int swq = (q ^ ((lr >> 1) & 3)) * 8;            // read-side swizzle

    f32x4 acc[4][4];
#pragma unroll
    for (int i = 0; i < 4; i++)
#pragma unroll
        for (int j = 0; j < 4; j++) acc[i][j] = (f32x4){0.f, 0.f, 0.f, 0.f};

    for (int k0 = 0; k0 < K; k0 += BK) {
        gl_lds16(Ar0 + k0, sA0);
        gl_lds16(Ar1 + k0, sA1);
        gl_lds16(Br0 + k0, sB0);
        gl_lds16(Br1 + k0, sB1);
        __syncthreads();

        bf16x8 af[4], bfr[4];
#pragma unroll
        for (int i = 0; i < 4; i++)
            af[i] = __builtin_bit_cast(bf16x8,
                *(const u32x4*)(&As[(wr * 64 + i * 16 + lr) * BK + swq]));
#pragma unroll
        for (int j = 0; j < 4; j++)
            bfr[j] = __builtin_bit_cast(bf16x8,
                *(const u32x4*)(&Bs[(wc * 64 + j * 16 + lr) * BK + swq]));
#pragma unroll
        for (int i = 0; i < 4; i++)
#pragma unroll
            for (int j = 0; j < 4; j++) {
                if constexpr (SWAP)
                    acc[i][j] = __builtin_amdgcn_mfma_f32_16x16x32_bf16(bfr[j], af[i], acc[i][j], 0, 0, 0);
                else
                    acc[i][j] = __builtin_amdgcn_mfma_f32_16x16x32_bf16(af[i], bfr[j], acc[i][j], 0, 0, 0);
            }
        __syncthreads();
    }

    if constexpr (SWAP) {
        // D layout (swapped): thread holds C[m0+..+lr][coln .. coln+3] -> vector stores
#pragma unroll
        for (int j = 0; j < 4; j++) {
            const int coln = n0 + wc * 64 + j * 16 + q * 4;
            float sc4[4], sh4[4];
            if constexpr (EPI == EPI_BIAS) {
                float bb[4]; ld4bf(p.bias + coln, bb);
#pragma unroll
                for (int r = 0; r < 4; r++) { sc4[r] = 1.f; sh4[r] = bb[r]; }
            } else if constexpr (EPI == EPI_SCALE) {
#pragma unroll
                for (int r = 0; r < 4; r++) { sc4[r] = p.alpha; sh4[r] = 0.f; }
            } else if constexpr (EPI == EPI_BN) {
                float bb[4], g[4], bt[4], mn[4], vr[4];
                ld4bf(p.bias + coln, bb); ld4bf(p.gamma + coln, g); ld4bf(p.beta + coln, bt);
                ld4bf(p.mean + coln, mn); ld4bf(p.var + coln, vr);
#pragma unroll
                for (int r = 0; r < 4; r++) {
                    const float s = g[r] * rsqrtf(vr[r] + 1e-3f);
                    sc4[r] = s;
                    sh4[r] = s * bb[r] + bt[r] - s * mn[r];
                }
            }
#pragma unroll
            for (int i = 0; i < 4; i++) {
                const int row = m0 + wr * 64 + i * 16 + lr;
                const long off = cbase + (long)row * ldc + coln;
                float v[4];
#pragma unroll
                for (int r = 0; r < 4; r++) v[r] = acc[i][j][r];
                if constexpr (EPI == EPI_BIASR) {
                    const float bs = bf2f(p.bias[row]);
#pragma unroll
                    for (int r = 0; r < 4; r++) v[r] += bs;
                } else if constexpr (EPI == EPI_BN) {
                    float rs[4]; ld4bf(p.res + (long)row * ldc + coln, rs);
#pragma unroll
                    for (int r = 0; r < 4; r++) v[r] = sc4[r] * v[r] + sh4[r] + rs[r];
                } else if constexpr (EPI != EPI_PART) {
#pragma unroll
                    for (int r = 0; r < 4; r++) v[r] = sc4[r] * v[r] + sh4[r];
                }
                if constexpr (EPI == EPI_PART) {
                    *(f32x4*)((float*)p.Cv + off) = (f32x4){v[0], v[1], v[2], v[3]};
                } else if constexpr (DYNOUT) {
                    if (isf32) *(f32x4*)((float*)p.Cv + off) = (f32x4){v[0], v[1], v[2], v[3]};
                    else       *(u32x2*)((ushort_t*)p.Cv + off) = pk4bf(v);
                } else {
                    *(u32x2*)((ushort_t*)p.Cv + off) = pk4bf(v);
                }
            }
        }
    } else {
        // D layout: col=lane&15 -> n, row=(lane>>4)*4+reg -> m  [verified]
        const bool doC = (n0 < p.cnmax);
#pragma unroll
        for (int j = 0; j < 4; j++) {
            const int col = n0 + wc * 64 + j * 16 + lr;
            float bs = 0.f, sc = 1.f, sh = 0.f;
            if constexpr (EPI == EPI_BIAS || EPI == EPI_BN) bs = bf2f(p.bias[col]);
            if constexpr (EPI == EPI_BN) {
                const float g  = bf2f(p.gamma[col]);
                const float bt = bf2f(p.beta[col]);
                const float mn = bf2f(p.mean[col]);
                const float vr = bf2f(p.var[col]);
                sc = g * rsqrtf(vr + 1e-3f);
                sh = bt - sc * mn;
            }
#pragma unroll
            for (int i = 0; i < 4; i++) {
                const int rowbase = m0 + wr * 64 + i * 16 + q * 4;
                ushort_t tmp[4];
#pragma unroll
                for (int r = 0; r < 4; r++) {
                    const int row = rowbase + r;
                    float v = acc[i][j][r];
                    if constexpr (EPI == EPI_BIAS) v += bs;
                    else if constexpr (EPI == EPI_BIASR) v += bf2f(p.bias[row]);
                    else if constexpr (EPI == EPI_SCALE) v *= p.alpha;
                    else if constexpr (EPI == EPI_BN)
                        v = sc * (v + bs) + sh + bf2f(p.res[(long)row * ldc + col]);
                    const long off = cbase + (long)row * ldc + col;
                    if constexpr (EPI == EPI_PART) {
                        ((float*)p.Cv)[off] = v;
                    } else if constexpr (DYNOUT) {
                        if (isf32) ((float*)p.Cv)[off] = v;
                        else       ((ushort_t*)p.Cv)[off] = f2bf(v);
                    } else {
                        const ushort_t us2 = f2bf(v);
                        tmp[r] = us2;
                        if (doC) ((ushort_t*)p.Cv)[off] = us2;
                    }
                }
                if constexpr (DUALT) {
                    u32x2 pk;
                    pk[0] = (uint32)tmp[0] | ((uint32)tmp[1] << 16);
                    pk[1] = (uint32)tmp[2] | ((uint32)tmp[3] << 16);
                    *(u32x2*)(p.CT + (long)col * p.ldT + rowbase) = pk;
                }
            }
        }
    }
}

extern "C" void kernel_launch(void* const* d_in, const int* in_sizes, int n_in,
                              void* d_out, int out_size, void* d_ws, size_t ws_size,
                              hipStream_t stream)
{
    int* flag = (int*)d_ws;
    ushort_t* base = (ushort_t*)((char*)d_ws + 16);
    long o = 0;
    ushort_t* detect_c = base + o; o += 16777216;   // [32768][512]
    ushort_t* aim_c    = base + o; o += 4194304;    // [8192][512]
    ushort_t* WpgT = base + o; o += 262144;         // [512][512] = [WpT; WgT]
    ushort_t* WtgT = base + o; o += 262144;         // [512][512] = [WtT; WgT]
    ushort_t* WwT  = base + o; o += 131072;         // [512][256]
    ushort_t* WqT  = base + o; o += 131072;
    ushort_t* bpg_c  = base + o; o += 512;          // [bp; bg]
    ushort_t* btg_c  = base + o; o += 512;          // [bt; bg]
    ushort_t* bw_c   = base + o; o += 512;
    ushort_t* gw_c   = base + o; o += 512;
    ushort_t* betw_c = base + o; o += 512;
    ushort_t* mw_c   = base + o; o += 512;
    ushort_t* vw_c   = base + o; o += 512;
    ushort_t* bq_c   = base + o; o += 512;
    ushort_t* gq_c   = base + o; o += 512;
    ushort_t* betq_c = base + o; o += 512;
    ushort_t* mq_c   = base + o; o += 512;
    ushort_t* vq_c   = base + o; o += 512;
    ushort_t* phi    = base + o; o += 8388608;      // [32768][256]
    ushort_t* PT     = base + o; o += 16777216;     // [512][32768]: rows 0-255 phiT, 256-511 d_xT
    ushort_t* theta  = base + o; o += 2097152;      // [8192][256]
    ushort_t* TT     = base + o; o += 4194304;      // [512][8192]: rows 0-255 thetaT, 256-511 a_xT
    ushort_t* G1T    = base + o; o += 524288;       // [8][256][256]
    ushort_t* G2T    = base + o; o += 524288;
    // union region: P1,P2 (fp32, 64 slices each, lifetime ends at reduce) then na,nd
    ushort_t* U      = base + o; o += 16777216;     // 32 MiB
    float* P1 = (float*)U;                          // 64 x 65536 fp32
    float* P2 = P1 + 4194304;
    ushort_t* na = U;                               // [8192][256]
    ushort_t* nd = na + 2097152;                    // [32768][256]
    ushort_t* phiT = PT;
    ushort_t* d_xT = PT + 8388608;
    ushort_t* thetaT = TT;
    ushort_t* a_xT = TT + 2097152;

    // canon: sniff + vectors fused (bg goes into both concat bias tails)
    VecArgs va;
    const int vidx[14] = {7, 3, 5, 3, 9, 10, 11, 12, 13, 15, 16, 17, 18, 19};
    ushort_t* vdst[14] = {bpg_c, bpg_c + 256, btg_c, btg_c + 256,
                          bw_c, gw_c, betw_c, mw_c, vw_c,
                          bq_c, gq_c, betq_c, mq_c, vq_c};
    const int vn[14] = {256, 256, 256, 256, 512, 512, 512, 512, 512, 512, 512, 512, 512, 512};
    for (int i = 0; i < 14; i++) { va.s[i] = d_in[vidx[i]]; va.d[i] = vdst[i]; va.n[i] = vn[i]; }
    sniff_vec_kernel<<<1, 256, 0, stream>>>((const uint32*)d_in[0], flag, va);

    WtArgs wa;
    wa.s[0] = d_in[6];  wa.d[0] = WpgT;              wa.R[0] = 512; wa.C[0] = 256;  // Wp^T -> rows 0-255
    wa.s[1] = d_in[2];  wa.d[1] = WpgT + 256 * 512;  wa.R[1] = 512; wa.C[1] = 256;  // Wg^T -> rows 256-511
    wa.s[2] = d_in[4];  wa.d[2] = WtgT;              wa.R[2] = 512; wa.C[2] = 256;  // Wt^T
    wa.s[3] = d_in[2];  wa.d[3] = WtgT + 256 * 512;  wa.R[3] = 512; wa.C[3] = 256;  // Wg^T
    wa.s[4] = d_in[8];  wa.d[4] = WwT;               wa.R[4] = 256; wa.C[4] = 512;
    wa.s[5] = d_in[14]; wa.d[5] = WqT;               wa.R[5] = 256; wa.C[5] = 512;
    canon_all<<<4608, 256, 0, stream>>>(d_in[0], detect_c, d_in[1], aim_c, wa, flag);

    const dim3 blk(256);
    const ushort_t* np = nullptr;
    ushort_t* npm = nullptr;

    // merged convs (one launch): set0 = detect conv (by<256), set1 = aim conv.
    // C = act @ [W?|Wg] (N=512); C-store only cols<256 (phi/theta); CT = full 512 rows
    // (phiT+d_xT / thetaT+a_xT). One read of each activation.
    {
        GP2 g;
        g.g[0] = GP{detect_c, WpgT, phi, PT, bpg_c, np, np, np, np, np,
                    0, 0, 0, 0, 512, 512, 512, 256, 256, 32768, 1.f};
        g.g[1] = GP{aim_c, WtgT, theta, TT, btg_c, np, np, np, np, np,
                    0, 0, 0, 0, 512, 512, 512, 256, 256, 8192, 1.f};
        gemm_nt<EPI_BIAS, false, true, false><<<dim3(4, 320, 1), blk, 0, stream>>>(
            g, 256, BIGN, flag);
    }

    // merged split-K partials (one launch): set0 = G1 (bz<64, K-chunk 512),
    // set1 = G2 (bz 64..127, K-chunk 128). 512 workgroups.
    {
        GP2 g;
        g.g[0] = GP{phiT, d_xT, P1, npm, np, np, np, np, np, np,
                    0, 512, 512, 65536, 512, 32768, 32768, 256, BIGN, 0, 1.f};
        g.g[1] = GP{thetaT, a_xT, P2, npm, np, np, np, np, np, np,
                    0, 128, 128, 65536, 128, 8192, 8192, 256, BIGN, 0, 1.f};
        gemm_nt<EPI_PART, false, false, true><<<dim3(2, 2, 128), blk, 0, stream>>>(
            g, BIGN, 64, flag);
    }

    reduce_t2_kernel<<<dim3(8, 8, 16), blk, 0, stream>>>(P1, P2, G1T, G2T);

    // merged nd/na (one launch): set0 = nd (by<32), set1 = na (by 32..39). z = batch.
    {
        GP2 g;
        g.g[0] = GP{phi, G2T, nd, npm, np, np, np, np, np, np,
                    0, 1048576, 65536, 1048576, 256, 256, 256, 256, BIGN, 0, 1.f / 1024.f};
        g.g[1] = GP{theta, G1T, na, npm, np, np, np, np, np, np,
                    0, 262144, 65536, 262144, 256, 256, 256, 256, BIGN, 0, 1.f / 4096.f};
        gemm_nt<EPI_SCALE, false, false, true><<<dim3(2, 40, 8), blk, 0, stream>>>(
            g, 32, BIGN, flag);
    }

    // merged outputs (one launch): set0 = out1 (by<256), set1 = out0.
    {
        GP2 g;
        g.g[0] = GP{nd, WqT, d_out, npm, bq_c, gq_c, betq_c, mq_c, vq_c, detect_c,
                    8192L * 512, 0, 0, 0, 256, 256, 256, 512, BIGN, 0, 1.f};
        g.g[1] = GP{na, WwT, d_out, npm, bw_c, gw_c, betw_c, mw_c, vw_c, aim_c,
                    0, 0, 0, 0, 256, 256, 256, 512, BIGN, 0, 1.f};
        gemm_nt<EPI_BN, true, false, true><<<dim3(4, 320, 1), blk, 0, stream>>>(
            g, 256, BIGN, flag);
    }
}

// Round 5
// 361.747 us; speedup vs baseline: 1.3291x; 1.0186x over previous
//
#include <hip/hip_runtime.h>

typedef unsigned short ushort_t;
typedef unsigned int uint32;
typedef __bf16 bf16x8 __attribute__((ext_vector_type(8)));
typedef float f32x4 __attribute__((ext_vector_type(4)));
typedef uint32 u32x4 __attribute__((ext_vector_type(4)));
typedef uint32 u32x2 __attribute__((ext_vector_type(2)));

typedef __attribute__((address_space(3))) uint32 as3_u32;
typedef const __attribute__((address_space(1))) uint32 as1_u32c;

// async global->LDS, 16B per lane; LDS dest = wave-uniform base + lane*16
__device__ __forceinline__ void gl_lds16(const ushort_t* g, ushort_t* l) {
    __builtin_amdgcn_global_load_lds((as1_u32c*)g, (as3_u32*)l, 16, 0, 0);
}

__device__ __forceinline__ float bf2f(ushort_t u) {
    uint32 x = ((uint32)u) << 16;
    return __builtin_bit_cast(float, x);
}
__device__ __forceinline__ ushort_t f2bf(float f) {
    uint32 x = __builtin_bit_cast(uint32, f);
    x += 0x7fffu + ((x >> 16) & 1u);   // RNE
    return (ushort_t)(x >> 16);
}
// load 4 consecutive bf16 -> 4 floats (8B vector load)
__device__ __forceinline__ void ld4bf(const ushort_t* p, float* f) {
    const u32x2 w = *(const u32x2*)p;
    f[0] = bf2f((ushort_t)(w[0] & 0xffffu)); f[1] = bf2f((ushort_t)(w[0] >> 16));
    f[2] = bf2f((ushort_t)(w[1] & 0xffffu)); f[3] = bf2f((ushort_t)(w[1] >> 16));
}
// pack 4 floats -> 4 bf16 (8B)
__device__ __forceinline__ u32x2 pk4bf(const float* v) {
    u32x2 pk;
    pk[0] = (uint32)f2bf(v[0]) | ((uint32)f2bf(v[1]) << 16);
    pk[1] = (uint32)f2bf(v[2]) | ((uint32)f2bf(v[3]) << 16);
    return pk;
}

// fused dtype-sniff + small-vector canon: 1 launch (14 segments; bg written twice
// into the two concatenated bias buffers)
struct VecArgs { const void* s[14]; ushort_t* d[14]; int n[14]; };
__global__ void sniff_vec_kernel(const uint32* __restrict__ src, int* __restrict__ flag,
                                 VecArgs a) {
    __shared__ int cnt;
    if (threadIdx.x == 0) cnt = 0;
    __syncthreads();
    if (threadIdx.x < 64) {
        int weird = 0;
        for (int c = 0; c < 4; c++) {
            uint32 w = src[threadIdx.x * 4 + c];
            uint32 e = (w >> 7) & 0xFFu;
            weird += (e < 64u) || (e >= 192u);
        }
        if (weird) atomicAdd(&cnt, weird);
    }
    __syncthreads();
    const bool isf32 = (cnt > 32);
    if (threadIdx.x == 0) *flag = isf32 ? 1 : 0;
    const int t = threadIdx.x;
    for (int seg = 0; seg < 14; seg++) {
        const int n = a.n[seg];
        if (isf32) {
            const float* s = (const float*)a.s[seg];
            for (int i = t; i < n; i += 256) a.d[seg][i] = f2bf(s[i]);
        } else {
            const ushort_t* s = (const ushort_t*)a.s[seg];
            for (int i = t; i < n; i += 256) a.d[seg][i] = s[i];
        }
    }
}

// all remaining canon work in ONE launch:
//   blocks [0,2048)      : detect activation canon (16.7M elems, vectorized x8)
//   blocks [2048,3072)   : aim activation canon (4.2M elems)
//   blocks [3072,4608)   : 6 weight transpose slices (256 blocks each, guarded)
struct WtArgs { const void* s[6]; ushort_t* d[6]; int R[6]; int C[6]; };
__global__ void canon_all(const void* __restrict__ dsrc, ushort_t* __restrict__ ddst,
                          const void* __restrict__ asrc, ushort_t* __restrict__ adst,
                          WtArgs wa, const int* __restrict__ flag) {
    const bool isf32 = (*flag != 0);
    const int b = blockIdx.x;
    if (b < 3072) {
        const void* src; ushort_t* dst; long n; int b0, nb;
        if (b < 2048) { src = dsrc; dst = ddst; n = 16777216; b0 = b; nb = 2048; }
        else          { src = asrc; dst = adst; n = 4194304;  b0 = b - 2048; nb = 1024; }
        long i = ((long)b0 * 256 + threadIdx.x) * 8;
        const long stride = (long)nb * 256 * 8;
        if (isf32) {
            const float* s = (const float*)src;
            for (; i < n; i += stride) {
                const f32x4 a = *(const f32x4*)(s + i);
                const f32x4 c = *(const f32x4*)(s + i + 4);
                u32x4 o;
                o[0] = (uint32)f2bf(a[0]) | ((uint32)f2bf(a[1]) << 16);
                o[1] = (uint32)f2bf(a[2]) | ((uint32)f2bf(a[3]) << 16);
                o[2] = (uint32)f2bf(c[0]) | ((uint32)f2bf(c[1]) << 16);
                o[3] = (uint32)f2bf(c[2]) | ((uint32)f2bf(c[3]) << 16);
                *(u32x4*)(dst + i) = o;
            }
        } else {
            const ushort_t* s = (const ushort_t*)src;
            for (; i < n; i += stride)
                *(u32x4*)(dst + i) = *(const u32x4*)(s + i);
        }
    } else {
        const int local = b - 3072;
        const int wsel = local >> 8;
        const int rem = local & 255;
        const int tr = rem >> 4, tc = rem & 15;
        const int R = wa.R[wsel], C = wa.C[wsel];
        if (tc * 32 >= C || tr * 32 >= R) return;   // block-uniform skip
        __shared__ float s[32][33];
        const int t = threadIdx.x;
        const int r = t >> 3, c4 = (t & 7) * 4;
        const long sbase = (long)(tr * 32 + r) * C + tc * 32 + c4;
        if (isf32) {
            const float* S = (const float*)wa.s[wsel];
            const f32x4 v = *(const f32x4*)(S + sbase);
            for (int u = 0; u < 4; u++) s[r][c4 + u] = v[u];
        } else {
            const ushort_t* S = (const ushort_t*)wa.s[wsel];
            for (int u = 0; u < 4; u++) s[r][c4 + u] = bf2f(S[sbase + u]);
        }
        __syncthreads();
        float tv[4];
        for (int u = 0; u < 4; u++) tv[u] = s[c4 + u][r];
        *(u32x2*)(wa.d[wsel] + (long)(tc * 32 + r) * R + tr * 32 + c4) = pk4bf(tv);
    }
}

// reduce 8 fp32 split-K partials + transposed bf16 store, both G matrices in one
// launch: zz<8 -> P1/G1T (b=zz), else P2/G2T (b=zz-8).
__global__ void reduce_t2_kernel(const float* __restrict__ P1, const float* __restrict__ P2,
                                 ushort_t* __restrict__ G1T, ushort_t* __restrict__ G2T) {
    __shared__ float s[32][33];
    const int zz = blockIdx.z;
    const float* P = (zz < 8) ? P1 : P2;
    ushort_t* out  = (zz < 8) ? G1T : G2T;
    const int b = zz & 7;
    const int tm = blockIdx.y, tn = blockIdx.x;
    const int t = threadIdx.x;
    const int r = t >> 3, c4 = (t & 7) * 4;
    const float* base = P + (long)b * 8 * 65536 + (long)(tm * 32 + r) * 256 + tn * 32 + c4;
    f32x4 acc = {0.f, 0.f, 0.f, 0.f};
    for (int kc = 0; kc < 8; kc++) acc += *(const f32x4*)(base + (long)kc * 65536);
    for (int u = 0; u < 4; u++) s[r][c4 + u] = acc[u];
    __syncthreads();
    float tv[4];
    for (int u = 0; u < 4; u++) tv[u] = s[c4 + u][r];
    *(u32x2*)(out + (long)b * 65536 + (long)(tn * 32 + r) * 256 + tm * 32 + c4) = pk4bf(tv);
}

#define BM 128
#define BN 128
#define BK 32
#define LDSH (BM * BK)
#define BIGN (1 << 30)

enum { EPI_BIAS = 0, EPI_BIASR = 1, EPI_SCALE = 2, EPI_BN = 3, EPI_PART = 4 };

// per-GEMM parameter set (two per launch; selected block-uniformly by y/z split)
struct GP {
    const ushort_t* A; const ushort_t* B; void* Cv; ushort_t* CT;
    const ushort_t* bias; const ushort_t* gamma; const ushort_t* beta;
    const ushort_t* mean; const ushort_t* var; const ushort_t* res;
    long coff, sA, sB, sC;
    int K, lda, ldb, ldc, cnmax, ldT;
    float alpha;
};
struct GP2 { GP g[2]; };

// NT GEMM: C[m][n] = sum_k A[m][k] * B[n][k], both operands k-contiguous.
// 2-phase double-buffered K-loop: prefetch tile t+1 via global_load_lds while
// computing tile t; counted s_waitcnt vmcnt(4) + raw s_barrier keep the prefetch
// in flight across the barrier (avoids __syncthreads' vmcnt(0) drain).
// Source unit index pre-swizzled (u ^= (row>>1)&3); same XOR on fragment reads.
// XCD-bijective block swizzle (nwg%8==0). Two fused sub-GEMMs per launch.
template <int EPI, bool DYNOUT, bool DUALT, bool SWAP>
__global__ __launch_bounds__(256) void gemm_nt(GP2 ga, int ysplit, int zsplit,
                                               const int* __restrict__ flag)
{
    __shared__ __align__(16) ushort_t As[2 * LDSH];
    __shared__ __align__(16) ushort_t Bs[2 * LDSH];

    const bool isf32 = DYNOUT ? (*flag != 0) : false;

    // XCD-aware bijective swizzle of the flattened block id (requires nwg%8==0)
    const uint32 gx = gridDim.x, gy = gridDim.y;
    const uint32 nwg = gx * gy * gridDim.z;
    const uint32 lid = blockIdx.x + gx * (blockIdx.y + gy * blockIdx.z);
    const uint32 swz = (lid & 7u) * (nwg >> 3) + (lid >> 3);
    const uint32 bx = swz % gx, t1 = swz / gx;
    int by = (int)(t1 % gy), bz = (int)(t1 / gy);

    int sel = 0;
    if (by >= ysplit) { by -= ysplit; sel = 1; }
    if (bz >= zsplit) { bz -= zsplit; sel = 1; }
    const GP& p = ga.g[sel];

    const ushort_t* A = p.A + (long)bz * p.sA;
    const ushort_t* B = p.B + (long)bz * p.sB;
    const long cbase = p.coff + (long)bz * p.sC;
    const int lda = p.lda, ldb = p.ldb, ldc = p.ldc, K = p.K;

    const int tid  = threadIdx.x;
    const int lane = tid & 63;
    const int w    = tid >> 6;
    const int wr   = w >> 1, wc = w & 1;
    const int lr   = lane & 15, q = lane >> 4;

    const int m0 = by * BM;
    const int n0 = bx * BN;

    // staging geometry: wave w covers rows [w*32, w*32+31] via two 1KB segments
    const int lrow = lane >> 2, lu = lane & 3;
    const int us = (lu ^ ((lrow >> 1) & 3)) * 8;          // source-side swizzle
    const int ra0 = w * 32 + lrow, ra1 = w * 32 + 16 + lrow;
    const ushort_t* Ar0 = A + (long)(m0 + ra0) * lda + us;
    const ushort_t* Ar1 = A + (long)(m0 + ra1) * lda + us;
    const ushort_t* Br0 = B + (long)(n0 + ra0) * ldb + us;
    const ushort_t* Br1 = B + (long)(n0 + ra1) * ldb + us;
    ushort_t* sA0 = &As[(w * 2 + 0) * 512];
    ushort_t* sA1 = &As[(w * 2 + 1) * 512];
    ushort_t* sB0 = &Bs[(w * 2 + 0) * 512];
    ushort_t* sB1 = &Bs[(w * 2 + 1) * 512];

    const int swq = (q ^ ((lr >> 1) & 3)) * 8;            // read-side swizzle

    f32x4 acc[4][4];
#pragma unroll
    for (int i = 0; i < 4; i++)
#pragma unroll
        for (int j = 0; j < 4; j++) acc[i][j] = (f32x4){0.f, 0.f, 0.f, 0.f};

    // prologue: stage tile 0 into buffer 0
    gl_lds16(Ar0, sA0);
    gl_lds16(Ar1, sA1);
    gl_lds16(Br0, sB0);
    gl_lds16(Br1, sB1);

    int cur = 0;
    for (int k0 = 0; k0 < K; k0 += BK, cur ^= 1) {
        const int kn = k0 + BK;
        if (kn < K) {
            const int nb = (cur ^ 1) * LDSH;
            gl_lds16(Ar0 + kn, sA0 + nb);
            gl_lds16(Ar1 + kn, sA1 + nb);
            gl_lds16(Br0 + kn, sB0 + nb);
            gl_lds16(Br1 + kn, sB1 + nb);
            asm volatile("s_waitcnt vmcnt(4)" ::: "memory");  // cur's 4 loads done
        } else {
            asm volatile("s_waitcnt vmcnt(0)" ::: "memory");
        }
        __builtin_amdgcn_s_barrier();
        __builtin_amdgcn_sched_barrier(0);

        const ushort_t* Ab = As + cur * LDSH;
        const ushort_t* Bb = Bs + cur * LDSH;
        bf16x8 af[4], bfr[4];
#pragma unroll
        for (int i = 0; i < 4; i++)
            af[i] = __builtin_bit_cast(bf16x8,
                *(const u32x4*)(&Ab[(wr * 64 + i * 16 + lr) * BK + swq]));
#pragma unroll
        for (int j = 0; j < 4; j++)
            bfr[j] = __builtin_bit_cast(bf16x8,
                *(const u32x4*)(&Bb[(wc * 64 + j * 16 + lr) * BK + swq]));
#pragma unroll
        for (int i = 0; i < 4; i++)
#pragma unroll
            for (int j = 0; j < 4; j++) {
                if constexpr (SWAP)
                    acc[i][j] = __builtin_amdgcn_mfma_f32_16x16x32_bf16(bfr[j], af[i], acc[i][j], 0, 0, 0);
                else
                    acc[i][j] = __builtin_amdgcn_mfma_f32_16x16x32_bf16(af[i], bfr[j], acc[i][j], 0, 0, 0);
            }

        __builtin_amdgcn_sched_barrier(0);
        asm volatile("" ::: "memory");
        __builtin_amdgcn_s_barrier();   // all waves done reading buf[cur] before
                                        // next iteration's stage overwrites it
    }

    if constexpr (SWAP) {
        // D layout (swapped): thread holds C[m0+..+lr][coln .. coln+3] -> vector stores
#pragma unroll
        for (int j = 0; j < 4; j++) {
            const int coln = n0 + wc * 64 + j * 16 + q * 4;
            float sc4[4], sh4[4];
            if constexpr (EPI == EPI_BIAS) {
                float bb[4]; ld4bf(p.bias + coln, bb);
#pragma unroll
                for (int r = 0; r < 4; r++) { sc4[r] = 1.f; sh4[r] = bb[r]; }
            } else if constexpr (EPI == EPI_SCALE) {
#pragma unroll
                for (int r = 0; r < 4; r++) { sc4[r] = p.alpha; sh4[r] = 0.f; }
            } else if constexpr (EPI == EPI_BN) {
                float bb[4], g[4], bt[4], mn[4], vr[4];
                ld4bf(p.bias + coln, bb); ld4bf(p.gamma + coln, g); ld4bf(p.beta + coln, bt);
                ld4bf(p.mean + coln, mn); ld4bf(p.var + coln, vr);
#pragma unroll
                for (int r = 0; r < 4; r++) {
                    const float s = g[r] * rsqrtf(vr[r] + 1e-3f);
                    sc4[r] = s;
                    sh4[r] = s * bb[r] + bt[r] - s * mn[r];
                }
            }
#pragma unroll
            for (int i = 0; i < 4; i++) {
                const int row = m0 + wr * 64 + i * 16 + lr;
                const long off = cbase + (long)row * ldc + coln;
                float v[4];
#pragma unroll
                for (int r = 0; r < 4; r++) v[r] = acc[i][j][r];
                if constexpr (EPI == EPI_BIASR) {
                    const float bs = bf2f(p.bias[row]);
#pragma unroll
                    for (int r = 0; r < 4; r++) v[r] += bs;
                } else if constexpr (EPI == EPI_BN) {
                    float rs[4]; ld4bf(p.res + (long)row * ldc + coln, rs);
#pragma unroll
                    for (int r = 0; r < 4; r++) v[r] = sc4[r] * v[r] + sh4[r] + rs[r];
                } else if constexpr (EPI != EPI_PART) {
#pragma unroll
                    for (int r = 0; r < 4; r++) v[r] = sc4[r] * v[r] + sh4[r];
                }
                if constexpr (EPI == EPI_PART) {
                    *(f32x4*)((float*)p.Cv + off) = (f32x4){v[0], v[1], v[2], v[3]};
                } else if constexpr (DYNOUT) {
                    if (isf32) *(f32x4*)((float*)p.Cv + off) = (f32x4){v[0], v[1], v[2], v[3]};
                    else       *(u32x2*)((ushort_t*)p.Cv + off) = pk4bf(v);
                } else {
                    *(u32x2*)((ushort_t*)p.Cv + off) = pk4bf(v);
                }
            }
        }
    } else {
        // D layout: col=lane&15 -> n, row=(lane>>4)*4+reg -> m  [verified]
        const bool doC = (n0 < p.cnmax);
#pragma unroll
        for (int j = 0; j < 4; j++) {
            const int col = n0 + wc * 64 + j * 16 + lr;
            float bs = 0.f, sc = 1.f, sh = 0.f;
            if constexpr (EPI == EPI_BIAS || EPI == EPI_BN) bs = bf2f(p.bias[col]);
            if constexpr (EPI == EPI_BN) {
                const float g  = bf2f(p.gamma[col]);
                const float bt = bf2f(p.beta[col]);
                const float mn = bf2f(p.mean[col]);
                const float vr = bf2f(p.var[col]);
                sc = g * rsqrtf(vr + 1e-3f);
                sh = bt - sc * mn;
            }
#pragma unroll
            for (int i = 0; i < 4; i++) {
                const int rowbase = m0 + wr * 64 + i * 16 + q * 4;
                ushort_t tmp[4];
#pragma unroll
                for (int r = 0; r < 4; r++) {
                    const int row = rowbase + r;
                    float v = acc[i][j][r];
                    if constexpr (EPI == EPI_BIAS) v += bs;
                    else if constexpr (EPI == EPI_BIASR) v += bf2f(p.bias[row]);
                    else if constexpr (EPI == EPI_SCALE) v *= p.alpha;
                    else if constexpr (EPI == EPI_BN)
                        v = sc * (v + bs) + sh + bf2f(p.res[(long)row * ldc + col]);
                    const long off = cbase + (long)row * ldc + col;
                    if constexpr (EPI == EPI_PART) {
                        ((float*)p.Cv)[off] = v;
                    } else if constexpr (DYNOUT) {
                        if (isf32) ((float*)p.Cv)[off] = v;
                        else       ((ushort_t*)p.Cv)[off] = f2bf(v);
                    } else {
                        const ushort_t us2 = f2bf(v);
                        tmp[r] = us2;
                        if (doC) ((ushort_t*)p.Cv)[off] = us2;
                    }
                }
                if constexpr (DUALT) {
                    u32x2 pk;
                    pk[0] = (uint32)tmp[0] | ((uint32)tmp[1] << 16);
                    pk[1] = (uint32)tmp[2] | ((uint32)tmp[3] << 16);
                    *(u32x2*)(p.CT + (long)col * p.ldT + rowbase) = pk;
                }
            }
        }
    }
}

extern "C" void kernel_launch(void* const* d_in, const int* in_sizes, int n_in,
                              void* d_out, int out_size, void* d_ws, size_t ws_size,
                              hipStream_t stream)
{
    int* flag = (int*)d_ws;
    ushort_t* base = (ushort_t*)((char*)d_ws + 16);
    long o = 0;
    ushort_t* detect_c = base + o; o += 16777216;   // [32768][512]
    ushort_t* aim_c    = base + o; o += 4194304;    // [8192][512]
    ushort_t* WpgT = base + o; o += 262144;         // [512][512] = [WpT; WgT]
    ushort_t* WtgT = base + o; o += 262144;         // [512][512] = [WtT; WgT]
    ushort_t* WwT  = base + o; o += 131072;         // [512][256]
    ushort_t* WqT  = base + o; o += 131072;
    ushort_t* bpg_c  = base + o; o += 512;          // [bp; bg]
    ushort_t* btg_c  = base + o; o += 512;          // [bt; bg]
    ushort_t* bw_c   = base + o; o += 512;
    ushort_t* gw_c   = base + o; o += 512;
    ushort_t* betw_c = base + o; o += 512;
    ushort_t* mw_c   = base + o; o += 512;
    ushort_t* vw_c   = base + o; o += 512;
    ushort_t* bq_c   = base + o; o += 512;
    ushort_t* gq_c   = base + o; o += 512;
    ushort_t* betq_c = base + o; o += 512;
    ushort_t* mq_c   = base + o; o += 512;
    ushort_t* vq_c   = base + o; o += 512;
    ushort_t* phi    = base + o; o += 8388608;      // [32768][256]
    ushort_t* PT     = base + o; o += 16777216;     // [512][32768]: rows 0-255 phiT, 256-511 d_xT
    ushort_t* theta  = base + o; o += 2097152;      // [8192][256]
    ushort_t* TT     = base + o; o += 4194304;      // [512][8192]: rows 0-255 thetaT, 256-511 a_xT
    ushort_t* G1T    = base + o; o += 524288;       // [8][256][256]
    ushort_t* G2T    = base + o; o += 524288;
    // union region: P1,P2 (fp32, 64 slices each, lifetime ends at reduce) then na,nd
    ushort_t* U      = base + o; o += 16777216;     // 32 MiB
    float* P1 = (float*)U;                          // 64 x 65536 fp32
    float* P2 = P1 + 4194304;
    ushort_t* na = U;                               // [8192][256]
    ushort_t* nd = na + 2097152;                    // [32768][256]
    ushort_t* phiT = PT;
    ushort_t* d_xT = PT + 8388608;
    ushort_t* thetaT = TT;
    ushort_t* a_xT = TT + 2097152;

    // canon: sniff + vectors fused (bg goes into both concat bias tails)
    VecArgs va;
    const int vidx[14] = {7, 3, 5, 3, 9, 10, 11, 12, 13, 15, 16, 17, 18, 19};
    ushort_t* vdst[14] = {bpg_c, bpg_c + 256, btg_c, btg_c + 256,
                          bw_c, gw_c, betw_c, mw_c, vw_c,
                          bq_c, gq_c, betq_c, mq_c, vq_c};
    const int vn[14] = {256, 256, 256, 256, 512, 512, 512, 512, 512, 512, 512, 512, 512, 512};
    for (int i = 0; i < 14; i++) { va.s[i] = d_in[vidx[i]]; va.d[i] = vdst[i]; va.n[i] = vn[i]; }
    sniff_vec_kernel<<<1, 256, 0, stream>>>((const uint32*)d_in[0], flag, va);

    WtArgs wa;
    wa.s[0] = d_in[6];  wa.d[0] = WpgT;              wa.R[0] = 512; wa.C[0] = 256;  // Wp^T -> rows 0-255
    wa.s[1] = d_in[2];  wa.d[1] = WpgT + 256 * 512;  wa.R[1] = 512; wa.C[1] = 256;  // Wg^T -> rows 256-511
    wa.s[2] = d_in[4];  wa.d[2] = WtgT;              wa.R[2] = 512; wa.C[2] = 256;  // Wt^T
    wa.s[3] = d_in[2];  wa.d[3] = WtgT + 256 * 512;  wa.R[3] = 512; wa.C[3] = 256;  // Wg^T
    wa.s[4] = d_in[8];  wa.d[4] = WwT;               wa.R[4] = 256; wa.C[4] = 512;
    wa.s[5] = d_in[14]; wa.d[5] = WqT;               wa.R[5] = 256; wa.C[5] = 512;
    canon_all<<<4608, 256, 0, stream>>>(d_in[0], detect_c, d_in[1], aim_c, wa, flag);

    const dim3 blk(256);
    const ushort_t* np = nullptr;
    ushort_t* npm = nullptr;

    // merged convs (one launch): set0 = detect conv (by<256), set1 = aim conv.
    // C = act @ [W?|Wg] (N=512); C-store only cols<256 (phi/theta); CT = full 512 rows
    // (phiT+d_xT / thetaT+a_xT). One read of each activation.
    {
        GP2 g;
        g.g[0] = GP{detect_c, WpgT, phi, PT, bpg_c, np, np, np, np, np,
                    0, 0, 0, 0, 512, 512, 512, 256, 256, 32768, 1.f};
        g.g[1] = GP{aim_c, WtgT, theta, TT, btg_c, np, np, np, np, np,
                    0, 0, 0, 0, 512, 512, 512, 256, 256, 8192, 1.f};
        gemm_nt<EPI_BIAS, false, true, false><<<dim3(4, 320, 1), blk, 0, stream>>>(
            g, 256, BIGN, flag);
    }

    // merged split-K partials (one launch): set0 = G1 (bz<64, K-chunk 512),
    // set1 = G2 (bz 64..127, K-chunk 128). 512 workgroups.
    {
        GP2 g;
        g.g[0] = GP{phiT, d_xT, P1, npm, np, np, np, np, np, np,
                    0, 512, 512, 65536, 512, 32768, 32768, 256, BIGN, 0, 1.f};
        g.g[1] = GP{thetaT, a_xT, P2, npm, np, np, np, np, np, np,
                    0, 128, 128, 65536, 128, 8192, 8192, 256, BIGN, 0, 1.f};
        gemm_nt<EPI_PART, false, false, true><<<dim3(2, 2, 128), blk, 0, stream>>>(
            g, BIGN, 64, flag);
    }

    reduce_t2_kernel<<<dim3(8, 8, 16), blk, 0, stream>>>(P1, P2, G1T, G2T);

    // merged nd/na (one launch): set0 = nd (by<32), set1 = na (by 32..39). z = batch.
    {
        GP2 g;
        g.g[0] = GP{phi, G2T, nd, npm, np, np, np, np, np, np,
                    0, 1048576, 65536, 1048576, 256, 256, 256, 256, BIGN, 0, 1.f / 1024.f};
        g.g[1] = GP{theta, G1T, na, npm, np, np, np, np, np, np,
                    0, 262144, 65536, 262144, 256, 256, 256, 256, BIGN, 0, 1.f / 4096.f};
        gemm_nt<EPI_SCALE, false, false, true><<<dim3(2, 40, 8), blk, 0, stream>>>(
            g, 32, BIGN, flag);
    }

    // merged outputs (one launch): set0 = out1 (by<256), set1 = out0.
    {
        GP2 g;
        g.g[0] = GP{nd, WqT, d_out, npm, bq_c, gq_c, betq_c, mq_c, vq_c, detect_c,
                    8192L * 512, 0, 0, 0, 256, 256, 256, 512, BIGN, 0, 1.f};
        g.g[1] = GP{na, WwT, d_out, npm, bw_c, gw_c, betw_c, mw_c, vw_c, aim_c,
                    0, 0, 0, 0, 256, 256, 256, 512, BIGN, 0, 1.f};
        gemm_nt<EPI_BN, true, false, true><<<dim3(4, 320, 1), blk, 0, stream>>>(
            g, 256, BIGN, flag);
    }
}